// Round 1
// baseline (848.087 us; speedup 1.0000x reference)
//
#include <hip/hip_runtime.h>
#include <math.h>

#define NN 100000
#define EE 1600000
#define ET (EE + NN)          // edges + self loops = 1,700,000
#define NB1 196               // ceil(NN/512)
#define NEG 0.2f

typedef float4 f4;

// ---------------- init: deg=1 (self loop), stats=0 ----------------
__global__ void k_init(int* deg, float* stats) {
    int i = blockIdx.x * blockDim.x + threadIdx.x;
    if (i < NN) deg[i] = 1;
    if (i < 4) stats[i] = 0.f;
}

// ---------------- BN statistics: sum / sumsq of 2 columns ----------------
__global__ void k_bnstats(const float* __restrict__ h, float* stats) {
    int gid = blockIdx.x * blockDim.x + threadIdx.x;
    int stride = gridDim.x * blockDim.x;
    float s0 = 0.f, s1 = 0.f, q0 = 0.f, q1 = 0.f;
    for (int i = gid; i < NN; i += stride) {
        float2 v = reinterpret_cast<const float2*>(h)[i];
        s0 += v.x; q0 += v.x * v.x;
        s1 += v.y; q1 += v.y * v.y;
    }
#pragma unroll
    for (int off = 32; off >= 1; off >>= 1) {
        s0 += __shfl_xor(s0, off);
        s1 += __shfl_xor(s1, off);
        q0 += __shfl_xor(q0, off);
        q1 += __shfl_xor(q1, off);
    }
    if ((threadIdx.x & 63) == 0) {
        atomicAdd(&stats[0], s0); atomicAdd(&stats[1], s1);
        atomicAdd(&stats[2], q0); atomicAdd(&stats[3], q1);
    }
}

// ---------------- in-degree count over real edges ----------------
__global__ void k_deg(const int* __restrict__ ei, int* deg) {
    int i = blockIdx.x * blockDim.x + threadIdx.x;
    int stride = gridDim.x * blockDim.x;
    for (; i < EE; i += stride) atomicAdd(&deg[ei[EE + i]], 1);
}

// ---------------- 3-kernel exclusive scan (rowptr) ----------------
__global__ void k_scan1(const int* __restrict__ deg, int* rowptr, int* bsums) {
    __shared__ int sm[512];
    int tid = threadIdx.x;
    int gid = blockIdx.x * 512 + tid;
    int v = (gid < NN) ? deg[gid] : 0;
    sm[tid] = v;
    __syncthreads();
    for (int off = 1; off < 512; off <<= 1) {
        int t = (tid >= off) ? sm[tid - off] : 0;
        __syncthreads();
        sm[tid] += t;
        __syncthreads();
    }
    if (gid < NN) rowptr[gid] = sm[tid] - v;          // exclusive
    if (tid == 511) bsums[blockIdx.x] = sm[511];      // block total
}

__global__ void k_scan2(int* bsums) {
    __shared__ int sm[256];
    int tid = threadIdx.x;
    int v = (tid < NB1) ? bsums[tid] : 0;
    sm[tid] = v;
    __syncthreads();
    for (int off = 1; off < 256; off <<= 1) {
        int t = (tid >= off) ? sm[tid - off] : 0;
        __syncthreads();
        sm[tid] += t;
        __syncthreads();
    }
    if (tid < NB1) bsums[tid] = sm[tid] - v;          // exclusive
}

__global__ void k_scan3(int* rowptr, const int* __restrict__ bsums, int* cursor) {
    int gid = blockIdx.x * 512 + threadIdx.x;
    if (gid < NN) {
        int r = rowptr[gid] + bsums[blockIdx.x];
        rowptr[gid] = r;
        cursor[gid] = r;
    }
    if (gid == 0) rowptr[NN] = ET;
}

// ---------------- scatter edges into CSR (store src only) ----------------
__global__ void k_scatter(const int* __restrict__ ei, int* cursor, int* __restrict__ srcl) {
    int i = blockIdx.x * blockDim.x + threadIdx.x;
    int stride = gridDim.x * blockDim.x;
    for (; i < ET; i += stride) {
        int s, d;
        if (i < EE) { s = ei[i]; d = ei[EE + i]; }
        else { s = i - EE; d = s; }
        int pos = atomicAdd(&cursor[d], 1);
        srcl[pos] = s;
    }
}

// ---------------- BN apply + linear(2->64) + attention scalars ----------------
__global__ void k_xform1(const float* __restrict__ h, const float* __restrict__ stats,
                         const float* __restrict__ gamma, const float* __restrict__ beta,
                         const float* __restrict__ W1, const float* __restrict__ a_s,
                         const float* __restrict__ a_d,
                         float* __restrict__ xp, float* __restrict__ es, float* __restrict__ ed) {
    int n = blockIdx.x * blockDim.x + threadIdx.x;
    if (n >= NN) return;
    const float inv = 1.f / (float)NN;
    float mu0 = stats[0] * inv, mu1 = stats[1] * inv;
    float v0 = stats[2] * inv - mu0 * mu0;
    float v1 = stats[3] * inv - mu1 * mu1;
    float g0 = rsqrtf(v0 + 1e-5f) * gamma[0];
    float g1 = rsqrtf(v1 + 1e-5f) * gamma[1];
    float2 hv = reinterpret_cast<const float2*>(h)[n];
    float x0 = (hv.x - mu0) * g0 + beta[0];
    float x1 = (hv.y - mu1) * g1 + beta[1];
    float vv[64];
    float es0 = 0.f, es1 = 0.f, ed0 = 0.f, ed1 = 0.f;
#pragma unroll
    for (int f = 0; f < 64; ++f) {
        float v = x0 * W1[2 * f] + x1 * W1[2 * f + 1];
        vv[f] = v;
        float ts = v * a_s[f], td = v * a_d[f];
        if (f < 32) { es0 += ts; ed0 += td; } else { es1 += ts; ed1 += td; }
    }
    f4* xo = reinterpret_cast<f4*>(xp + (size_t)n * 64);
#pragma unroll
    for (int q = 0; q < 16; ++q)
        xo[q] = make_float4(vv[4 * q], vv[4 * q + 1], vv[4 * q + 2], vv[4 * q + 3]);
    es[2 * n] = es0; es[2 * n + 1] = es1;
    ed[2 * n] = ed0; ed[2 * n + 1] = ed1;
}

// ---------------- GAT aggregation: one wave per dst node, online softmax ----------------
__global__ void __launch_bounds__(256) k_gat(
    const float* __restrict__ xp, const float* __restrict__ es, const float* __restrict__ ed,
    const int* __restrict__ rowptr, const int* __restrict__ srcl,
    const float* __restrict__ bias, float* __restrict__ out) {
    int wid = (blockIdx.x * blockDim.x + threadIdx.x) >> 6;   // wave id == node
    int lane = threadIdx.x & 63;
    if (wid >= NN) return;
    int n = wid;
    int head = lane >> 5;
    int beg = rowptr[n], end = rowptr[n + 1];
    float edn = ed[2 * n + head];
    float m = -1e30f, sum = 0.f, acc = 0.f;
    for (int k = beg; k < end; ++k) {
        int s = srcl[k];
        float e = es[2 * s + head] + edn;
        e = (e > 0.f) ? e : NEG * e;                          // leaky relu
        float xv = xp[(size_t)s * 64 + lane];
        float mn = fmaxf(m, e);
        float sc = __expf(m - mn);
        float w  = __expf(e - mn);
        sum = sum * sc + w;
        acc = acc * sc + w * xv;
        m = mn;
    }
    float r = acc / (sum + 1e-16f) + bias[lane];
    out[(size_t)n * 64 + lane] = fmaxf(r, 0.f);               // post-GAT ReLU (both layers)
}

// ---------------- linear(64->64) + attention scalars (for GAT layer 2) ----------------
__global__ void k_xform2(const float* __restrict__ hin, const float* __restrict__ W,
                         const float* __restrict__ a_s, const float* __restrict__ a_d,
                         float* __restrict__ xp, float* __restrict__ es, float* __restrict__ ed) {
    int n = blockIdx.x * blockDim.x + threadIdx.x;
    if (n >= NN) return;
    float x[64];
    const f4* xi = reinterpret_cast<const f4*>(hin + (size_t)n * 64);
#pragma unroll
    for (int q = 0; q < 16; ++q) {
        f4 t = xi[q];
        x[4 * q] = t.x; x[4 * q + 1] = t.y; x[4 * q + 2] = t.z; x[4 * q + 3] = t.w;
    }
    float es0 = 0.f, es1 = 0.f, ed0 = 0.f, ed1 = 0.f;
    f4* xo = reinterpret_cast<f4*>(xp + (size_t)n * 64);
#pragma unroll 1
    for (int fq = 0; fq < 16; ++fq) {
        float vq[4];
#pragma unroll
        for (int j = 0; j < 4; ++j) {
            int f = 4 * fq + j;
            float acc = 0.f;
#pragma unroll
            for (int i = 0; i < 64; ++i) acc += W[f * 64 + i] * x[i];
            vq[j] = acc;
            float ts = acc * a_s[f], td = acc * a_d[f];
            if (fq < 8) { es0 += ts; ed0 += td; } else { es1 += ts; ed1 += td; }
        }
        xo[fq] = make_float4(vq[0], vq[1], vq[2], vq[3]);
    }
    es[2 * n] = es0; es[2 * n + 1] = es1;
    ed[2 * n] = ed0; ed[2 * n + 1] = ed1;
}

// ---------------- fused 5-layer MLP, thread per node ----------------
__device__ __forceinline__ void layer64(const float* __restrict__ W, const float* __restrict__ B,
                                        const float* x, float* y) {
#pragma unroll
    for (int o = 0; o < 64; ++o) {
        float acc = B[o];
#pragma unroll
        for (int i = 0; i < 64; ++i) acc += W[o * 64 + i] * x[i];
        y[o] = fmaxf(acc, 0.f);
    }
}

__global__ void __launch_bounds__(256) k_mlp(
    const float* __restrict__ hin,
    const float* __restrict__ w1, const float* __restrict__ b1,
    const float* __restrict__ w2, const float* __restrict__ b2,
    const float* __restrict__ w3, const float* __restrict__ b3,
    const float* __restrict__ w4, const float* __restrict__ b4,
    const float* __restrict__ w5, const float* __restrict__ b5,
    float* __restrict__ out) {
    int n = blockIdx.x * blockDim.x + threadIdx.x;
    if (n >= NN) return;
    float x[64], y[64];
    const f4* xi = reinterpret_cast<const f4*>(hin + (size_t)n * 64);
#pragma unroll
    for (int q = 0; q < 16; ++q) {
        f4 t = xi[q];
        x[4 * q] = t.x; x[4 * q + 1] = t.y; x[4 * q + 2] = t.z; x[4 * q + 3] = t.w;
    }
    layer64(w1, b1, x, y);
    layer64(w2, b2, y, x);
    layer64(w3, b3, x, y);
    layer64(w4, b4, y, x);
    float o11[11];
#pragma unroll
    for (int o = 0; o < 11; ++o) {
        float acc = b5[o];
#pragma unroll
        for (int i = 0; i < 64; ++i) acc += w5[o * 64 + i] * x[i];
        o11[o] = acc;
    }
    float* op = out + (size_t)n * 11;
#pragma unroll
    for (int o = 0; o < 11; ++o) op[o] = o11[o];
}

// ---------------- launch ----------------
extern "C" void kernel_launch(void* const* d_in, const int* in_sizes, int n_in,
                              void* d_out, int out_size, void* d_ws, size_t ws_size,
                              hipStream_t stream) {
    const float* h   = (const float*)d_in[0];
    const int*   ei  = (const int*)d_in[1];
    const float* gam = (const float*)d_in[2];
    const float* bet = (const float*)d_in[3];
    const float* W1  = (const float*)d_in[4];
    const float* as1 = (const float*)d_in[5];
    const float* ad1 = (const float*)d_in[6];
    const float* b1  = (const float*)d_in[7];
    const float* W2  = (const float*)d_in[8];
    const float* as2 = (const float*)d_in[9];
    const float* ad2 = (const float*)d_in[10];
    const float* b2  = (const float*)d_in[11];
    const float* fw1 = (const float*)d_in[12];
    const float* fb1 = (const float*)d_in[13];
    const float* fw2 = (const float*)d_in[14];
    const float* fb2 = (const float*)d_in[15];
    const float* fw3 = (const float*)d_in[16];
    const float* fb3 = (const float*)d_in[17];
    const float* fw4 = (const float*)d_in[18];
    const float* fb4 = (const float*)d_in[19];
    const float* fw5 = (const float*)d_in[20];
    const float* fb5 = (const float*)d_in[21];
    float* out = (float*)d_out;

    char* ws = (char*)d_ws;
    size_t off = 0;
    auto alloc = [&](size_t bytes) -> char* {
        char* p = ws + off;
        off += (bytes + 255) & ~(size_t)255;
        return p;
    };
    float* stats  = (float*)alloc(4 * sizeof(float));
    int*   deg    = (int*)alloc((size_t)NN * sizeof(int));
    int*   rowptr = (int*)alloc((size_t)(NN + 1) * sizeof(int));
    int*   cursor = (int*)alloc((size_t)NN * sizeof(int));
    int*   bsums  = (int*)alloc(256 * sizeof(int));
    int*   srcl   = (int*)alloc((size_t)ET * sizeof(int));
    float* es     = (float*)alloc((size_t)NN * 2 * sizeof(float));
    float* ed     = (float*)alloc((size_t)NN * 2 * sizeof(float));
    float* bufA   = (float*)alloc((size_t)NN * 64 * sizeof(float));
    float* bufB   = (float*)alloc((size_t)NN * 64 * sizeof(float));
    (void)ws_size; (void)in_sizes; (void)n_in; (void)out_size;

    k_init<<<(NN + 255) / 256, 256, 0, stream>>>(deg, stats);
    k_bnstats<<<256, 256, 0, stream>>>(h, stats);
    k_deg<<<1024, 256, 0, stream>>>(ei, deg);
    k_scan1<<<NB1, 512, 0, stream>>>(deg, rowptr, bsums);
    k_scan2<<<1, 256, 0, stream>>>(bsums);
    k_scan3<<<NB1, 512, 0, stream>>>(rowptr, bsums, cursor);
    k_scatter<<<2048, 256, 0, stream>>>(ei, cursor, srcl);

    // GAT layer 1 (input = BN(h))
    k_xform1<<<(NN + 255) / 256, 256, 0, stream>>>(h, stats, gam, bet, W1, as1, ad1,
                                                   bufA, es, ed);
    k_gat<<<(NN * 64) / 256, 256, 0, stream>>>(bufA, es, ed, rowptr, srcl, b1, bufB);

    // GAT layer 2 (input = bufB)
    k_xform2<<<(NN + 255) / 256, 256, 0, stream>>>(bufB, W2, as2, ad2, bufA, es, ed);
    k_gat<<<(NN * 64) / 256, 256, 0, stream>>>(bufA, es, ed, rowptr, srcl, b2, bufB);

    // MLP head
    k_mlp<<<(NN + 255) / 256, 256, 0, stream>>>(bufB, fw1, fb1, fw2, fb2, fw3, fb3,
                                                fw4, fb4, fw5, fb5, out);
}

// Round 2
// 628.015 us; speedup vs baseline: 1.3504x; 1.3504x over previous
//
#include <hip/hip_runtime.h>
#include <math.h>

#define NN 100000
#define EE 1600000
#define ET (EE + NN)          // edges + self loops = 1,700,000
#define NB1 196               // ceil(NN/512)
#define NEG 0.2f
#define MSTR 68               // LDS row stride (floats), 16B-aligned, 2-way-ish conflicts

typedef float4 f4;

// ---------------- init: deg=1 (self loop), stats=0 ----------------
__global__ void k_init(int* deg, float* stats) {
    int i = blockIdx.x * blockDim.x + threadIdx.x;
    if (i < NN) deg[i] = 1;
    if (i < 4) stats[i] = 0.f;
}

// ---------------- BN statistics: sum / sumsq of 2 columns ----------------
__global__ void k_bnstats(const float* __restrict__ h, float* stats) {
    int gid = blockIdx.x * blockDim.x + threadIdx.x;
    int stride = gridDim.x * blockDim.x;
    float s0 = 0.f, s1 = 0.f, q0 = 0.f, q1 = 0.f;
    for (int i = gid; i < NN; i += stride) {
        float2 v = reinterpret_cast<const float2*>(h)[i];
        s0 += v.x; q0 += v.x * v.x;
        s1 += v.y; q1 += v.y * v.y;
    }
#pragma unroll
    for (int off = 32; off >= 1; off >>= 1) {
        s0 += __shfl_xor(s0, off);
        s1 += __shfl_xor(s1, off);
        q0 += __shfl_xor(q0, off);
        q1 += __shfl_xor(q1, off);
    }
    if ((threadIdx.x & 63) == 0) {
        atomicAdd(&stats[0], s0); atomicAdd(&stats[1], s1);
        atomicAdd(&stats[2], q0); atomicAdd(&stats[3], q1);
    }
}

// ---------------- in-degree count over real edges ----------------
__global__ void k_deg(const int* __restrict__ ei, int* deg) {
    int i = blockIdx.x * blockDim.x + threadIdx.x;
    int stride = gridDim.x * blockDim.x;
    for (; i < EE; i += stride) atomicAdd(&deg[ei[EE + i]], 1);
}

// ---------------- 3-kernel exclusive scan (rowptr) ----------------
__global__ void k_scan1(const int* __restrict__ deg, int* rowptr, int* bsums) {
    __shared__ int sm[512];
    int tid = threadIdx.x;
    int gid = blockIdx.x * 512 + tid;
    int v = (gid < NN) ? deg[gid] : 0;
    sm[tid] = v;
    __syncthreads();
    for (int off = 1; off < 512; off <<= 1) {
        int t = (tid >= off) ? sm[tid - off] : 0;
        __syncthreads();
        sm[tid] += t;
        __syncthreads();
    }
    if (gid < NN) rowptr[gid] = sm[tid] - v;          // exclusive
    if (tid == 511) bsums[blockIdx.x] = sm[511];      // block total
}

__global__ void k_scan2(int* bsums) {
    __shared__ int sm[256];
    int tid = threadIdx.x;
    int v = (tid < NB1) ? bsums[tid] : 0;
    sm[tid] = v;
    __syncthreads();
    for (int off = 1; off < 256; off <<= 1) {
        int t = (tid >= off) ? sm[tid - off] : 0;
        __syncthreads();
        sm[tid] += t;
        __syncthreads();
    }
    if (tid < NB1) bsums[tid] = sm[tid] - v;          // exclusive
}

__global__ void k_scan3(int* rowptr, const int* __restrict__ bsums, int* cursor) {
    int gid = blockIdx.x * 512 + threadIdx.x;
    if (gid < NN) {
        int r = rowptr[gid] + bsums[blockIdx.x];
        rowptr[gid] = r;
        cursor[gid] = r;
    }
    if (gid == 0) rowptr[NN] = ET;
}

// ---------------- scatter edges into CSR (store src only) ----------------
__global__ void k_scatter(const int* __restrict__ ei, int* cursor, int* __restrict__ srcl) {
    int i = blockIdx.x * blockDim.x + threadIdx.x;
    int stride = gridDim.x * blockDim.x;
    for (; i < ET; i += stride) {
        int s, d;
        if (i < EE) { s = ei[i]; d = ei[EE + i]; }
        else { s = i - EE; d = s; }
        int pos = atomicAdd(&cursor[d], 1);
        srcl[pos] = s;
    }
}

// ---------------- BN apply + linear(2->64) + attention scalars ----------------
__global__ void k_xform1(const float* __restrict__ h, const float* __restrict__ stats,
                         const float* __restrict__ gamma, const float* __restrict__ beta,
                         const float* __restrict__ W1, const float* __restrict__ a_s,
                         const float* __restrict__ a_d,
                         float* __restrict__ xp, float* __restrict__ es, float* __restrict__ ed) {
    int n = blockIdx.x * blockDim.x + threadIdx.x;
    if (n >= NN) return;
    const float inv = 1.f / (float)NN;
    float mu0 = stats[0] * inv, mu1 = stats[1] * inv;
    float v0 = stats[2] * inv - mu0 * mu0;
    float v1 = stats[3] * inv - mu1 * mu1;
    float g0 = rsqrtf(v0 + 1e-5f) * gamma[0];
    float g1 = rsqrtf(v1 + 1e-5f) * gamma[1];
    float2 hv = reinterpret_cast<const float2*>(h)[n];
    float x0 = (hv.x - mu0) * g0 + beta[0];
    float x1 = (hv.y - mu1) * g1 + beta[1];
    float vv[64];
    float es0 = 0.f, es1 = 0.f, ed0 = 0.f, ed1 = 0.f;
#pragma unroll
    for (int f = 0; f < 64; ++f) {
        float v = x0 * W1[2 * f] + x1 * W1[2 * f + 1];
        vv[f] = v;
        float ts = v * a_s[f], td = v * a_d[f];
        if (f < 32) { es0 += ts; ed0 += td; } else { es1 += ts; ed1 += td; }
    }
    f4* xo = reinterpret_cast<f4*>(xp + (size_t)n * 64);
#pragma unroll
    for (int q = 0; q < 16; ++q)
        xo[q] = make_float4(vv[4 * q], vv[4 * q + 1], vv[4 * q + 2], vv[4 * q + 3]);
    es[2 * n] = es0; es[2 * n + 1] = es1;
    ed[2 * n] = ed0; ed[2 * n + 1] = ed1;
}

// ---------------- GAT aggregation: one wave per dst node, online softmax ----------------
__global__ void __launch_bounds__(256) k_gat(
    const float* __restrict__ xp, const float* __restrict__ es, const float* __restrict__ ed,
    const int* __restrict__ rowptr, const int* __restrict__ srcl,
    const float* __restrict__ bias, float* __restrict__ out) {
    int wid = (blockIdx.x * blockDim.x + threadIdx.x) >> 6;   // wave id == node
    int lane = threadIdx.x & 63;
    if (wid >= NN) return;
    int n = wid;
    int head = lane >> 5;
    int beg = rowptr[n], end = rowptr[n + 1];
    float edn = ed[2 * n + head];
    float m = -1e30f, sum = 0.f, acc = 0.f;
    int k = beg;
    // unrolled-by-2: two gathers in flight, 3 exp per 2 edges
    for (; k + 2 <= end; k += 2) {
        int s0 = srcl[k], s1 = srcl[k + 1];
        float e0 = es[2 * s0 + head] + edn;
        float e1 = es[2 * s1 + head] + edn;
        float x0 = xp[(size_t)s0 * 64 + lane];
        float x1 = xp[(size_t)s1 * 64 + lane];
        e0 = (e0 > 0.f) ? e0 : NEG * e0;
        e1 = (e1 > 0.f) ? e1 : NEG * e1;
        float mn = fmaxf(m, fmaxf(e0, e1));
        float sc = __expf(m - mn);
        float w0 = __expf(e0 - mn);
        float w1 = __expf(e1 - mn);
        sum = sum * sc + w0 + w1;
        acc = acc * sc + w0 * x0 + w1 * x1;
        m = mn;
    }
    if (k < end) {
        int s = srcl[k];
        float e = es[2 * s + head] + edn;
        e = (e > 0.f) ? e : NEG * e;
        float xv = xp[(size_t)s * 64 + lane];
        float mn = fmaxf(m, e);
        float sc = __expf(m - mn);
        float w  = __expf(e - mn);
        sum = sum * sc + w;
        acc = acc * sc + w * xv;
        m = mn;
    }
    float r = acc / (sum + 1e-16f) + bias[lane];
    out[(size_t)n * 64 + lane] = fmaxf(r, 0.f);               // post-GAT ReLU (both layers)
}

// ---------------- linear(64->64) + attention scalars (for GAT layer 2) ----------------
__global__ void k_xform2(const float* __restrict__ hin, const float* __restrict__ W,
                         const float* __restrict__ a_s, const float* __restrict__ a_d,
                         float* __restrict__ xp, float* __restrict__ es, float* __restrict__ ed) {
    int n = blockIdx.x * blockDim.x + threadIdx.x;
    if (n >= NN) return;
    float x[64];
    const f4* xi = reinterpret_cast<const f4*>(hin + (size_t)n * 64);
#pragma unroll
    for (int q = 0; q < 16; ++q) {
        f4 t = xi[q];
        x[4 * q] = t.x; x[4 * q + 1] = t.y; x[4 * q + 2] = t.z; x[4 * q + 3] = t.w;
    }
    float es0 = 0.f, es1 = 0.f, ed0 = 0.f, ed1 = 0.f;
    f4* xo = reinterpret_cast<f4*>(xp + (size_t)n * 64);
#pragma unroll 1
    for (int fq = 0; fq < 16; ++fq) {
        float vq[4];
#pragma unroll
        for (int j = 0; j < 4; ++j) {
            int f = 4 * fq + j;
            float acc = 0.f;
#pragma unroll
            for (int i = 0; i < 64; ++i) acc += W[f * 64 + i] * x[i];
            vq[j] = acc;
            float ts = acc * a_s[f], td = acc * a_d[f];
            if (fq < 8) { es0 += ts; ed0 += td; } else { es1 += ts; ed1 += td; }
        }
        xo[fq] = make_float4(vq[0], vq[1], vq[2], vq[3]);
    }
    es[2 * n] = es0; es[2 * n + 1] = es1;
    ed[2 * n] = ed0; ed[2 * n + 1] = ed1;
}

// ---------------- fused 5-layer MLP: 4 waves/block, wave w owns output quarter w,
// ---------------- lane = node (64 nodes per block), LDS activation exchange ----------------
__device__ __forceinline__ void mquarter(const float* __restrict__ W, const float* __restrict__ B,
                                         int o0, const float* x, float* acc) {
#pragma unroll
    for (int j = 0; j < 16; ++j) acc[j] = B[o0 + j];
#pragma unroll
    for (int i = 0; i < 64; ++i) {
        float xi = x[i];
#pragma unroll
        for (int j = 0; j < 16; ++j) acc[j] += W[(o0 + j) * 64 + i] * xi;
    }
}

__global__ void __launch_bounds__(256) k_mlp(
    const float* __restrict__ hin,
    const float* __restrict__ w1, const float* __restrict__ b1,
    const float* __restrict__ w2, const float* __restrict__ b2,
    const float* __restrict__ w3, const float* __restrict__ b3,
    const float* __restrict__ w4, const float* __restrict__ b4,
    const float* __restrict__ w5, const float* __restrict__ b5,
    float* __restrict__ out) {
    __shared__ float xs[64 * MSTR];
    int lane = threadIdx.x & 63;
    int w = __builtin_amdgcn_readfirstlane(threadIdx.x >> 6);   // wave id: SGPR -> scalar weight loads
    int nodeBase = blockIdx.x * 64;
    int node = nodeBase + lane;
    int o0 = w * 16;

    // cooperative, coalesced load of 64 nodes x 64 floats into LDS
#pragma unroll
    for (int i = 0; i < 4; ++i) {
        int v = threadIdx.x + 256 * i;          // f4 id within block tile
        int nl = v >> 4;                        // local node
        int f = (v & 15) << 2;                  // feature
        f4 t4 = make_float4(0.f, 0.f, 0.f, 0.f);
        if (nodeBase + nl < NN)
            t4 = reinterpret_cast<const f4*>(hin)[(size_t)(nodeBase + nl) * 16 + (v & 15)];
        *reinterpret_cast<f4*>(&xs[nl * MSTR + f]) = t4;
    }
    __syncthreads();

    float x[64];
#pragma unroll
    for (int q = 0; q < 16; ++q) {
        f4 t = *reinterpret_cast<const f4*>(&xs[lane * MSTR + 4 * q]);
        x[4 * q] = t.x; x[4 * q + 1] = t.y; x[4 * q + 2] = t.z; x[4 * q + 3] = t.w;
    }

    float acc[16];
#define MLP_LAYER(Wp, Bp)                                                        \
    mquarter(Wp, Bp, o0, x, acc);                                                \
    __syncthreads(); /* all lanes done reading previous activations */           \
    _Pragma("unroll")                                                            \
    for (int j = 0; j < 16; j += 4)                                              \
        *reinterpret_cast<f4*>(&xs[lane * MSTR + o0 + j]) =                      \
            make_float4(fmaxf(acc[j], 0.f), fmaxf(acc[j + 1], 0.f),              \
                        fmaxf(acc[j + 2], 0.f), fmaxf(acc[j + 3], 0.f));         \
    __syncthreads();                                                             \
    _Pragma("unroll")                                                            \
    for (int q = 0; q < 16; ++q) {                                               \
        f4 t = *reinterpret_cast<const f4*>(&xs[lane * MSTR + 4 * q]);           \
        x[4 * q] = t.x; x[4 * q + 1] = t.y; x[4 * q + 2] = t.z; x[4 * q + 3] = t.w; \
    }

    MLP_LAYER(w1, b1)
    MLP_LAYER(w2, b2)
    MLP_LAYER(w3, b3)
    MLP_LAYER(w4, b4)
#undef MLP_LAYER

    // final 64 -> 11 layer: wave w computes outputs [3w, 3w+ocnt)
    int ocnt = (w == 3) ? 2 : 3;
    int ob = w * 3;
    float a5[3];
#pragma unroll
    for (int j = 0; j < 3; ++j) {
        float a = 0.f;
        if (j < ocnt) {
            a = b5[ob + j];
#pragma unroll
            for (int i = 0; i < 64; ++i) a += w5[(ob + j) * 64 + i] * x[i];
        }
        a5[j] = a;
    }
    if (node < NN) {
        for (int j = 0; j < ocnt; ++j) out[(size_t)node * 11 + ob + j] = a5[j];
    }
}

// ---------------- launch ----------------
extern "C" void kernel_launch(void* const* d_in, const int* in_sizes, int n_in,
                              void* d_out, int out_size, void* d_ws, size_t ws_size,
                              hipStream_t stream) {
    const float* h   = (const float*)d_in[0];
    const int*   ei  = (const int*)d_in[1];
    const float* gam = (const float*)d_in[2];
    const float* bet = (const float*)d_in[3];
    const float* W1  = (const float*)d_in[4];
    const float* as1 = (const float*)d_in[5];
    const float* ad1 = (const float*)d_in[6];
    const float* b1  = (const float*)d_in[7];
    const float* W2  = (const float*)d_in[8];
    const float* as2 = (const float*)d_in[9];
    const float* ad2 = (const float*)d_in[10];
    const float* b2  = (const float*)d_in[11];
    const float* fw1 = (const float*)d_in[12];
    const float* fb1 = (const float*)d_in[13];
    const float* fw2 = (const float*)d_in[14];
    const float* fb2 = (const float*)d_in[15];
    const float* fw3 = (const float*)d_in[16];
    const float* fb3 = (const float*)d_in[17];
    const float* fw4 = (const float*)d_in[18];
    const float* fb4 = (const float*)d_in[19];
    const float* fw5 = (const float*)d_in[20];
    const float* fb5 = (const float*)d_in[21];
    float* out = (float*)d_out;

    char* ws = (char*)d_ws;
    size_t off = 0;
    auto alloc = [&](size_t bytes) -> char* {
        char* p = ws + off;
        off += (bytes + 255) & ~(size_t)255;
        return p;
    };
    float* stats  = (float*)alloc(4 * sizeof(float));
    int*   deg    = (int*)alloc((size_t)NN * sizeof(int));
    int*   rowptr = (int*)alloc((size_t)(NN + 1) * sizeof(int));
    int*   cursor = (int*)alloc((size_t)NN * sizeof(int));
    int*   bsums  = (int*)alloc(256 * sizeof(int));
    int*   srcl   = (int*)alloc((size_t)ET * sizeof(int));
    float* es     = (float*)alloc((size_t)NN * 2 * sizeof(float));
    float* ed     = (float*)alloc((size_t)NN * 2 * sizeof(float));
    float* bufA   = (float*)alloc((size_t)NN * 64 * sizeof(float));
    float* bufB   = (float*)alloc((size_t)NN * 64 * sizeof(float));
    (void)ws_size; (void)in_sizes; (void)n_in; (void)out_size;

    k_init<<<(NN + 255) / 256, 256, 0, stream>>>(deg, stats);
    k_bnstats<<<256, 256, 0, stream>>>(h, stats);
    k_deg<<<1024, 256, 0, stream>>>(ei, deg);
    k_scan1<<<NB1, 512, 0, stream>>>(deg, rowptr, bsums);
    k_scan2<<<1, 256, 0, stream>>>(bsums);
    k_scan3<<<NB1, 512, 0, stream>>>(rowptr, bsums, cursor);
    k_scatter<<<2048, 256, 0, stream>>>(ei, cursor, srcl);

    // GAT layer 1 (input = BN(h))
    k_xform1<<<(NN + 255) / 256, 256, 0, stream>>>(h, stats, gam, bet, W1, as1, ad1,
                                                   bufA, es, ed);
    k_gat<<<(NN * 64) / 256, 256, 0, stream>>>(bufA, es, ed, rowptr, srcl, b1, bufB);

    // GAT layer 2 (input = bufB)
    k_xform2<<<(NN + 255) / 256, 256, 0, stream>>>(bufB, W2, as2, ad2, bufA, es, ed);
    k_gat<<<(NN * 64) / 256, 256, 0, stream>>>(bufA, es, ed, rowptr, srcl, b2, bufB);

    // MLP head: 64 nodes per block, 4 waves each owning an output quarter
    k_mlp<<<(NN + 63) / 64, 256, 0, stream>>>(bufB, fw1, fb1, fw2, fb2, fw3, fb3,
                                              fw4, fb4, fw5, fb5, out);
}

// Round 3
// 480.998 us; speedup vs baseline: 1.7632x; 1.3056x over previous
//
#include <hip/hip_runtime.h>
#include <math.h>

#define NN 100000
#define EE 1600000
#define ET (EE + NN)          // edges + self loops = 1,700,000
#define NEG 0.2f
#define MSTR 68               // k_mlp LDS row stride (floats)

// CSR-build geometry
#define NBUCK 98              // ceil(NN/1024) buckets of 1024 dst nodes
#define NBLK 416              // ceil(ET/4096) partition blocks
#define BITEMS 4096           // items per partition block (256 thr x 16)

typedef float4 f4;

// ---------------- init: stats=0 ----------------
__global__ void k_init(float* stats) {
    int i = threadIdx.x;
    if (i < 4) stats[i] = 0.f;
}

// ---------------- BN statistics: sum / sumsq of 2 columns ----------------
__global__ void k_bnstats(const float* __restrict__ h, float* stats) {
    int gid = blockIdx.x * blockDim.x + threadIdx.x;
    int stride = gridDim.x * blockDim.x;
    float s0 = 0.f, s1 = 0.f, q0 = 0.f, q1 = 0.f;
    for (int i = gid; i < NN; i += stride) {
        float2 v = reinterpret_cast<const float2*>(h)[i];
        s0 += v.x; q0 += v.x * v.x;
        s1 += v.y; q1 += v.y * v.y;
    }
#pragma unroll
    for (int off = 32; off >= 1; off >>= 1) {
        s0 += __shfl_xor(s0, off);
        s1 += __shfl_xor(s1, off);
        q0 += __shfl_xor(q0, off);
        q1 += __shfl_xor(q1, off);
    }
    if ((threadIdx.x & 63) == 0) {
        atomicAdd(&stats[0], s0); atomicAdd(&stats[1], s1);
        atomicAdd(&stats[2], q0); atomicAdd(&stats[3], q1);
    }
}

// ---------------- CSR pass A: per-block bucket histogram ----------------
__global__ void __launch_bounds__(256) k_hist(const int* __restrict__ ei, int* __restrict__ H) {
    __shared__ int hist[NBUCK];
    int tid = threadIdx.x, blk = blockIdx.x;
    if (tid < NBUCK) hist[tid] = 0;
    __syncthreads();
    int base = blk * BITEMS;
#pragma unroll
    for (int it = 0; it < 16; ++it) {
        int i = base + it * 256 + tid;
        if (i < ET) {
            int d = (i < EE) ? ei[EE + i] : (i - EE);
            atomicAdd(&hist[d >> 10], 1);
        }
    }
    __syncthreads();
    if (tid < NBUCK) H[tid * NBLK + blk] = hist[tid];
}

// ---------------- CSR pass B1: bucket totals + base offsets (1 block) ----------------
__global__ void __launch_bounds__(1024) k_bscan1(const int* __restrict__ H, int* __restrict__ boff) {
    __shared__ int part[1024];
    __shared__ int btot[NBUCK];
    int tid = threadIdx.x;
    int b = tid >> 3, k = tid & 7;
    int s = 0;
    if (b < NBUCK)
        for (int blk = k; blk < NBLK; blk += 8) s += H[b * NBLK + blk];
    part[tid] = s;
    __syncthreads();
    if (tid < NBUCK) {
        int t = 0;
#pragma unroll
        for (int j = 0; j < 8; ++j) t += part[tid * 8 + j];
        btot[tid] = t;
    }
    __syncthreads();
    if (tid == 0) {
        int run = 0;
        for (int bb = 0; bb < NBUCK; ++bb) { boff[bb] = run; run += btot[bb]; }
        boff[NBUCK] = ET;
    }
}

// ---------------- CSR pass B2: per-(bucket,block) absolute offsets ----------------
__global__ void __launch_bounds__(64) k_bscan2(int* __restrict__ H, const int* __restrict__ boff) {
    int b = blockIdx.x, lane = threadIdx.x;
    int s = 0;
    int base_i = lane * 7;
#pragma unroll
    for (int j = 0; j < 7; ++j) {
        int idx = base_i + j;
        if (idx < NBLK) s += H[b * NBLK + idx];
    }
    int incl = s;
#pragma unroll
    for (int d = 1; d < 64; d <<= 1) {
        int n = __shfl_up(incl, d, 64);
        if (lane >= d) incl += n;
    }
    int run = boff[b] + incl - s;
#pragma unroll
    for (int j = 0; j < 7; ++j) {
        int idx = base_i + j;
        if (idx < NBLK) {
            int t = H[b * NBLK + idx];
            H[b * NBLK + idx] = run;
            run += t;
        }
    }
}

// ---------------- CSR pass C: partition edges into bucket regions ----------------
__global__ void __launch_bounds__(256) k_part(const int* __restrict__ ei, const int* __restrict__ H,
                                              unsigned* __restrict__ pairs) {
    __shared__ int cur[NBUCK];
    int tid = threadIdx.x, blk = blockIdx.x;
    if (tid < NBUCK) cur[tid] = H[tid * NBLK + blk];
    __syncthreads();
    int base = blk * BITEMS;
#pragma unroll
    for (int it = 0; it < 16; ++it) {
        int i = base + it * 256 + tid;
        if (i < ET) {
            int s, d;
            if (i < EE) { s = ei[i]; d = ei[EE + i]; }
            else { s = d = i - EE; }
            int b = d >> 10;
            int pos = atomicAdd(&cur[b], 1);
            pairs[pos] = (unsigned)s | ((unsigned)(d & 1023) << 17);
        }
    }
}

// ---------------- CSR pass D: per-bucket local CSR (rowptr + srcl) ----------------
__global__ void __launch_bounds__(1024) k_bucket(const unsigned* __restrict__ pairs,
                                                 const int* __restrict__ boff,
                                                 int* __restrict__ rowptr, int* __restrict__ srcl) {
    __shared__ int sh[1024];
    __shared__ int se[1024];
    int b = blockIdx.x, tid = threadIdx.x;
    int bb = boff[b], be = boff[b + 1];
    sh[tid] = 0;
    __syncthreads();
    for (int k = bb + tid; k < be; k += 1024) atomicAdd(&sh[pairs[k] >> 17], 1);
    __syncthreads();
    int deg = sh[tid];
    se[tid] = deg;
    __syncthreads();
    for (int off = 1; off < 1024; off <<= 1) {
        int t = (tid >= off) ? se[tid - off] : 0;
        __syncthreads();
        se[tid] += t;
        __syncthreads();
    }
    int excl = se[tid] - deg;
    int node = (b << 10) + tid;
    if (node < NN) rowptr[node] = bb + excl;
    sh[tid] = bb + excl;     // cursor
    __syncthreads();
    for (int k = bb + tid; k < be; k += 1024) {
        unsigned p = pairs[k];
        int pos = atomicAdd(&sh[p >> 17], 1);
        srcl[pos] = (int)(p & 0x1FFFFu);
    }
    if (b == 0 && tid == 0) rowptr[NN] = ET;
}

// ---------------- BN apply + linear(2->64) + attention scalars ----------------
__global__ void k_xform1(const float* __restrict__ h, const float* __restrict__ stats,
                         const float* __restrict__ gamma, const float* __restrict__ beta,
                         const float* __restrict__ W1, const float* __restrict__ a_s,
                         const float* __restrict__ a_d,
                         float* __restrict__ xp, float* __restrict__ es, float* __restrict__ ed) {
    int n = blockIdx.x * blockDim.x + threadIdx.x;
    if (n >= NN) return;
    const float inv = 1.f / (float)NN;
    float mu0 = stats[0] * inv, mu1 = stats[1] * inv;
    float v0 = stats[2] * inv - mu0 * mu0;
    float v1 = stats[3] * inv - mu1 * mu1;
    float g0 = rsqrtf(v0 + 1e-5f) * gamma[0];
    float g1 = rsqrtf(v1 + 1e-5f) * gamma[1];
    float2 hv = reinterpret_cast<const float2*>(h)[n];
    float x0 = (hv.x - mu0) * g0 + beta[0];
    float x1 = (hv.y - mu1) * g1 + beta[1];
    float vv[64];
    float es0 = 0.f, es1 = 0.f, ed0 = 0.f, ed1 = 0.f;
#pragma unroll
    for (int f = 0; f < 64; ++f) {
        float v = x0 * W1[2 * f] + x1 * W1[2 * f + 1];
        vv[f] = v;
        float ts = v * a_s[f], td = v * a_d[f];
        if (f < 32) { es0 += ts; ed0 += td; } else { es1 += ts; ed1 += td; }
    }
    f4* xo = reinterpret_cast<f4*>(xp + (size_t)n * 64);
#pragma unroll
    for (int q = 0; q < 16; ++q)
        xo[q] = make_float4(vv[4 * q], vv[4 * q + 1], vv[4 * q + 2], vv[4 * q + 3]);
    es[2 * n] = es0; es[2 * n + 1] = es1;
    ed[2 * n] = ed0; ed[2 * n + 1] = ed1;
}

// ---------------- GAT aggregation: one wave per dst node, online softmax ----------------
__global__ void __launch_bounds__(256) k_gat(
    const float* __restrict__ xp, const float* __restrict__ es, const float* __restrict__ ed,
    const int* __restrict__ rowptr, const int* __restrict__ srcl,
    const float* __restrict__ bias, float* __restrict__ out) {
    int wid = (blockIdx.x * blockDim.x + threadIdx.x) >> 6;   // wave id == node
    int lane = threadIdx.x & 63;
    if (wid >= NN) return;
    int n = wid;
    int head = lane >> 5;
    int beg = rowptr[n], end = rowptr[n + 1];
    float edn = ed[2 * n + head];
    float m = -1e30f, sum = 0.f, acc = 0.f;
    int k = beg;
    for (; k + 2 <= end; k += 2) {
        int s0 = srcl[k], s1 = srcl[k + 1];
        float e0 = es[2 * s0 + head] + edn;
        float e1 = es[2 * s1 + head] + edn;
        float x0 = xp[(size_t)s0 * 64 + lane];
        float x1 = xp[(size_t)s1 * 64 + lane];
        e0 = (e0 > 0.f) ? e0 : NEG * e0;
        e1 = (e1 > 0.f) ? e1 : NEG * e1;
        float mn = fmaxf(m, fmaxf(e0, e1));
        float sc = __expf(m - mn);
        float w0 = __expf(e0 - mn);
        float w1 = __expf(e1 - mn);
        sum = sum * sc + w0 + w1;
        acc = acc * sc + w0 * x0 + w1 * x1;
        m = mn;
    }
    if (k < end) {
        int s = srcl[k];
        float e = es[2 * s + head] + edn;
        e = (e > 0.f) ? e : NEG * e;
        float xv = xp[(size_t)s * 64 + lane];
        float mn = fmaxf(m, e);
        float sc = __expf(m - mn);
        float w  = __expf(e - mn);
        sum = sum * sc + w;
        acc = acc * sc + w * xv;
        m = mn;
    }
    float r = acc / (sum + 1e-16f) + bias[lane];
    out[(size_t)n * 64 + lane] = fmaxf(r, 0.f);               // post-GAT ReLU (both layers)
}

// ---------------- linear(64->64) + attention scalars (for GAT layer 2) ----------------
__global__ void k_xform2(const float* __restrict__ hin, const float* __restrict__ W,
                         const float* __restrict__ a_s, const float* __restrict__ a_d,
                         float* __restrict__ xp, float* __restrict__ es, float* __restrict__ ed) {
    int n = blockIdx.x * blockDim.x + threadIdx.x;
    if (n >= NN) return;
    float x[64];
    const f4* xi = reinterpret_cast<const f4*>(hin + (size_t)n * 64);
#pragma unroll
    for (int q = 0; q < 16; ++q) {
        f4 t = xi[q];
        x[4 * q] = t.x; x[4 * q + 1] = t.y; x[4 * q + 2] = t.z; x[4 * q + 3] = t.w;
    }
    float es0 = 0.f, es1 = 0.f, ed0 = 0.f, ed1 = 0.f;
    f4* xo = reinterpret_cast<f4*>(xp + (size_t)n * 64);
#pragma unroll 1
    for (int fq = 0; fq < 16; ++fq) {
        float vq[4];
#pragma unroll
        for (int j = 0; j < 4; ++j) {
            int f = 4 * fq + j;
            float acc = 0.f;
#pragma unroll
            for (int i = 0; i < 64; ++i) acc += W[f * 64 + i] * x[i];
            vq[j] = acc;
            float ts = acc * a_s[f], td = acc * a_d[f];
            if (fq < 8) { es0 += ts; ed0 += td; } else { es1 += ts; ed1 += td; }
        }
        xo[fq] = make_float4(vq[0], vq[1], vq[2], vq[3]);
    }
    es[2 * n] = es0; es[2 * n + 1] = es1;
    ed[2 * n] = ed0; ed[2 * n + 1] = ed1;
}

// ---------------- fused 5-layer MLP: 4 waves/block, wave w owns output quarter w ----------------
__device__ __forceinline__ void mquarter(const float* __restrict__ W, const float* __restrict__ B,
                                         int o0, const float* x, float* acc) {
#pragma unroll
    for (int j = 0; j < 16; ++j) acc[j] = B[o0 + j];
#pragma unroll
    for (int i = 0; i < 64; ++i) {
        float xi = x[i];
#pragma unroll
        for (int j = 0; j < 16; ++j) acc[j] += W[(o0 + j) * 64 + i] * xi;
    }
}

__global__ void __launch_bounds__(256) k_mlp(
    const float* __restrict__ hin,
    const float* __restrict__ w1, const float* __restrict__ b1,
    const float* __restrict__ w2, const float* __restrict__ b2,
    const float* __restrict__ w3, const float* __restrict__ b3,
    const float* __restrict__ w4, const float* __restrict__ b4,
    const float* __restrict__ w5, const float* __restrict__ b5,
    float* __restrict__ out) {
    __shared__ float xs[64 * MSTR];
    int lane = threadIdx.x & 63;
    int w = __builtin_amdgcn_readfirstlane(threadIdx.x >> 6);
    int nodeBase = blockIdx.x * 64;
    int node = nodeBase + lane;
    int o0 = w * 16;

#pragma unroll
    for (int i = 0; i < 4; ++i) {
        int v = threadIdx.x + 256 * i;
        int nl = v >> 4;
        int f = (v & 15) << 2;
        f4 t4 = make_float4(0.f, 0.f, 0.f, 0.f);
        if (nodeBase + nl < NN)
            t4 = reinterpret_cast<const f4*>(hin)[(size_t)(nodeBase + nl) * 16 + (v & 15)];
        *reinterpret_cast<f4*>(&xs[nl * MSTR + f]) = t4;
    }
    __syncthreads();

    float x[64];
#pragma unroll
    for (int q = 0; q < 16; ++q) {
        f4 t = *reinterpret_cast<const f4*>(&xs[lane * MSTR + 4 * q]);
        x[4 * q] = t.x; x[4 * q + 1] = t.y; x[4 * q + 2] = t.z; x[4 * q + 3] = t.w;
    }

    float acc[16];
#define MLP_LAYER(Wp, Bp)                                                        \
    mquarter(Wp, Bp, o0, x, acc);                                                \
    __syncthreads();                                                             \
    _Pragma("unroll")                                                            \
    for (int j = 0; j < 16; j += 4)                                              \
        *reinterpret_cast<f4*>(&xs[lane * MSTR + o0 + j]) =                      \
            make_float4(fmaxf(acc[j], 0.f), fmaxf(acc[j + 1], 0.f),              \
                        fmaxf(acc[j + 2], 0.f), fmaxf(acc[j + 3], 0.f));         \
    __syncthreads();                                                             \
    _Pragma("unroll")                                                            \
    for (int q = 0; q < 16; ++q) {                                               \
        f4 t = *reinterpret_cast<const f4*>(&xs[lane * MSTR + 4 * q]);           \
        x[4 * q] = t.x; x[4 * q + 1] = t.y; x[4 * q + 2] = t.z; x[4 * q + 3] = t.w; \
    }

    MLP_LAYER(w1, b1)
    MLP_LAYER(w2, b2)
    MLP_LAYER(w3, b3)
    MLP_LAYER(w4, b4)
#undef MLP_LAYER

    int ocnt = (w == 3) ? 2 : 3;
    int ob = w * 3;
    float a5[3];
#pragma unroll
    for (int j = 0; j < 3; ++j) {
        float a = 0.f;
        if (j < ocnt) {
            a = b5[ob + j];
#pragma unroll
            for (int i = 0; i < 64; ++i) a += w5[(ob + j) * 64 + i] * x[i];
        }
        a5[j] = a;
    }
    if (node < NN) {
        for (int j = 0; j < ocnt; ++j) out[(size_t)node * 11 + ob + j] = a5[j];
    }
}

// ---------------- launch ----------------
extern "C" void kernel_launch(void* const* d_in, const int* in_sizes, int n_in,
                              void* d_out, int out_size, void* d_ws, size_t ws_size,
                              hipStream_t stream) {
    const float* h   = (const float*)d_in[0];
    const int*   ei  = (const int*)d_in[1];
    const float* gam = (const float*)d_in[2];
    const float* bet = (const float*)d_in[3];
    const float* W1  = (const float*)d_in[4];
    const float* as1 = (const float*)d_in[5];
    const float* ad1 = (const float*)d_in[6];
    const float* b1  = (const float*)d_in[7];
    const float* W2  = (const float*)d_in[8];
    const float* as2 = (const float*)d_in[9];
    const float* ad2 = (const float*)d_in[10];
    const float* b2  = (const float*)d_in[11];
    const float* fw1 = (const float*)d_in[12];
    const float* fb1 = (const float*)d_in[13];
    const float* fw2 = (const float*)d_in[14];
    const float* fb2 = (const float*)d_in[15];
    const float* fw3 = (const float*)d_in[16];
    const float* fb3 = (const float*)d_in[17];
    const float* fw4 = (const float*)d_in[18];
    const float* fb4 = (const float*)d_in[19];
    const float* fw5 = (const float*)d_in[20];
    const float* fb5 = (const float*)d_in[21];
    float* out = (float*)d_out;

    char* ws = (char*)d_ws;
    size_t off = 0;
    auto alloc = [&](size_t bytes) -> char* {
        char* p = ws + off;
        off += (bytes + 255) & ~(size_t)255;
        return p;
    };
    float* stats  = (float*)alloc(4 * sizeof(float));
    int*   H      = (int*)alloc((size_t)NBUCK * NBLK * sizeof(int));
    int*   boff   = (int*)alloc((size_t)(NBUCK + 1) * sizeof(int));
    int*   rowptr = (int*)alloc((size_t)(NN + 1) * sizeof(int));
    int*   srcl   = (int*)alloc((size_t)ET * sizeof(int));
    float* es     = (float*)alloc((size_t)NN * 2 * sizeof(float));
    float* ed     = (float*)alloc((size_t)NN * 2 * sizeof(float));
    float* bufA   = (float*)alloc((size_t)NN * 64 * sizeof(float));
    float* bufB   = (float*)alloc((size_t)NN * 64 * sizeof(float));
    unsigned* pairs = (unsigned*)bufA;   // alias: pairs dead before k_xform1 writes bufA
    (void)ws_size; (void)in_sizes; (void)n_in; (void)out_size;

    k_init<<<1, 64, 0, stream>>>(stats);
    k_bnstats<<<256, 256, 0, stream>>>(h, stats);

    // CSR build: hist -> scan -> partition -> per-bucket CSR
    k_hist<<<NBLK, 256, 0, stream>>>(ei, H);
    k_bscan1<<<1, 1024, 0, stream>>>(H, boff);
    k_bscan2<<<NBUCK, 64, 0, stream>>>(H, boff);
    k_part<<<NBLK, 256, 0, stream>>>(ei, H, pairs);
    k_bucket<<<NBUCK, 1024, 0, stream>>>(pairs, boff, rowptr, srcl);

    // GAT layer 1 (input = BN(h))
    k_xform1<<<(NN + 255) / 256, 256, 0, stream>>>(h, stats, gam, bet, W1, as1, ad1,
                                                   bufA, es, ed);
    k_gat<<<(NN * 64) / 256, 256, 0, stream>>>(bufA, es, ed, rowptr, srcl, b1, bufB);

    // GAT layer 2 (input = bufB)
    k_xform2<<<(NN + 255) / 256, 256, 0, stream>>>(bufB, W2, as2, ad2, bufA, es, ed);
    k_gat<<<(NN * 64) / 256, 256, 0, stream>>>(bufA, es, ed, rowptr, srcl, b2, bufB);

    // MLP head
    k_mlp<<<(NN + 63) / 64, 256, 0, stream>>>(bufB, fw1, fb1, fw2, fb2, fw3, fb3,
                                              fw4, fb4, fw5, fb5, out);
}

// Round 4
// 393.842 us; speedup vs baseline: 2.1534x; 1.2213x over previous
//
#include <hip/hip_runtime.h>
#include <math.h>

#define NN 100000
#define EE 1600000
#define ET (EE + NN)          // edges + self loops = 1,700,000
#define NEG 0.2f
#define MSTR 68               // k_mlp LDS row stride (floats); 68%32=4 -> no 32-way conflicts

// CSR-build geometry
#define NBUCK 98              // ceil(NN/1024) buckets of 1024 dst nodes
#define NBLK 416              // ceil(ET/4096) partition blocks
#define BITEMS 4096           // items per partition block (256 thr x 16)

typedef float4 f4;

// ---------------- init: stats=0 ----------------
__global__ void k_init(float* stats) {
    int i = threadIdx.x;
    if (i < 4) stats[i] = 0.f;
}

// ---------------- BN statistics: sum / sumsq of 2 columns ----------------
__global__ void k_bnstats(const float* __restrict__ h, float* stats) {
    int gid = blockIdx.x * blockDim.x + threadIdx.x;
    int stride = gridDim.x * blockDim.x;
    float s0 = 0.f, s1 = 0.f, q0 = 0.f, q1 = 0.f;
    for (int i = gid; i < NN; i += stride) {
        float2 v = reinterpret_cast<const float2*>(h)[i];
        s0 += v.x; q0 += v.x * v.x;
        s1 += v.y; q1 += v.y * v.y;
    }
#pragma unroll
    for (int off = 32; off >= 1; off >>= 1) {
        s0 += __shfl_xor(s0, off);
        s1 += __shfl_xor(s1, off);
        q0 += __shfl_xor(q0, off);
        q1 += __shfl_xor(q1, off);
    }
    if ((threadIdx.x & 63) == 0) {
        atomicAdd(&stats[0], s0); atomicAdd(&stats[1], s1);
        atomicAdd(&stats[2], q0); atomicAdd(&stats[3], q1);
    }
}

// ---------------- pack MLP weights for wave-uniform contiguous s_load streams ----------------
// Wt[L][q][i][j] = W_L[(q*16+j)*64 + i]   (L<4, q<4, i<64, j<16)
// Wt5[i][4w+j]   = w5[(3w+j)*64 + i]      (padded with zeros)
__global__ void k_wprep(const float* __restrict__ w1, const float* __restrict__ w2,
                        const float* __restrict__ w3, const float* __restrict__ w4,
                        const float* __restrict__ w5,
                        float* __restrict__ Wt, float* __restrict__ Wt5) {
    int idx = blockIdx.x * blockDim.x + threadIdx.x;
    if (idx < 4 * 4096) {
        int L = idx >> 12;
        int r = idx & 4095;
        int q = r >> 10;
        int t = r & 1023;
        int i = t >> 4, j = t & 15;
        const float* W = (L == 0) ? w1 : (L == 1) ? w2 : (L == 2) ? w3 : w4;
        Wt[idx] = W[(q * 16 + j) * 64 + i];
    }
    if (idx < 1024) {
        int i = idx >> 4, c = idx & 15;
        int w = c >> 2, j = c & 3;
        int o = 3 * w + j;
        int ocnt = (w == 3) ? 2 : 3;
        Wt5[idx] = (j < ocnt) ? w5[o * 64 + i] : 0.f;
    }
}

// ---------------- CSR pass A: per-block bucket histogram ----------------
__global__ void __launch_bounds__(256) k_hist(const int* __restrict__ ei, int* __restrict__ H) {
    __shared__ int hist[NBUCK];
    int tid = threadIdx.x, blk = blockIdx.x;
    if (tid < NBUCK) hist[tid] = 0;
    __syncthreads();
    int base = blk * BITEMS;
#pragma unroll
    for (int it = 0; it < 16; ++it) {
        int i = base + it * 256 + tid;
        if (i < ET) {
            int d = (i < EE) ? ei[EE + i] : (i - EE);
            atomicAdd(&hist[d >> 10], 1);
        }
    }
    __syncthreads();
    if (tid < NBUCK) H[tid * NBLK + blk] = hist[tid];
}

// ---------------- CSR pass B1: bucket totals + base offsets (1 block) ----------------
__global__ void __launch_bounds__(1024) k_bscan1(const int* __restrict__ H, int* __restrict__ boff) {
    __shared__ int part[1024];
    __shared__ int btot[NBUCK];
    int tid = threadIdx.x;
    int b = tid >> 3, k = tid & 7;
    int s = 0;
    if (b < NBUCK)
        for (int blk = k; blk < NBLK; blk += 8) s += H[b * NBLK + blk];
    part[tid] = s;
    __syncthreads();
    if (tid < NBUCK) {
        int t = 0;
#pragma unroll
        for (int j = 0; j < 8; ++j) t += part[tid * 8 + j];
        btot[tid] = t;
    }
    __syncthreads();
    if (tid == 0) {
        int run = 0;
        for (int bb = 0; bb < NBUCK; ++bb) { boff[bb] = run; run += btot[bb]; }
        boff[NBUCK] = ET;
    }
}

// ---------------- CSR pass B2: per-(bucket,block) absolute offsets ----------------
__global__ void __launch_bounds__(64) k_bscan2(int* __restrict__ H, const int* __restrict__ boff) {
    int b = blockIdx.x, lane = threadIdx.x;
    int s = 0;
    int base_i = lane * 7;
#pragma unroll
    for (int j = 0; j < 7; ++j) {
        int idx = base_i + j;
        if (idx < NBLK) s += H[b * NBLK + idx];
    }
    int incl = s;
#pragma unroll
    for (int d = 1; d < 64; d <<= 1) {
        int n = __shfl_up(incl, d, 64);
        if (lane >= d) incl += n;
    }
    int run = boff[b] + incl - s;
#pragma unroll
    for (int j = 0; j < 7; ++j) {
        int idx = base_i + j;
        if (idx < NBLK) {
            int t = H[b * NBLK + idx];
            H[b * NBLK + idx] = run;
            run += t;
        }
    }
}

// ---------------- CSR pass C: partition edges into bucket regions ----------------
__global__ void __launch_bounds__(256) k_part(const int* __restrict__ ei, const int* __restrict__ H,
                                              unsigned* __restrict__ pairs) {
    __shared__ int cur[NBUCK];
    int tid = threadIdx.x, blk = blockIdx.x;
    if (tid < NBUCK) cur[tid] = H[tid * NBLK + blk];
    __syncthreads();
    int base = blk * BITEMS;
#pragma unroll
    for (int it = 0; it < 16; ++it) {
        int i = base + it * 256 + tid;
        if (i < ET) {
            int s, d;
            if (i < EE) { s = ei[i]; d = ei[EE + i]; }
            else { s = d = i - EE; }
            int b = d >> 10;
            int pos = atomicAdd(&cur[b], 1);
            pairs[pos] = (unsigned)s | ((unsigned)(d & 1023) << 17);
        }
    }
}

// ---------------- CSR pass D: per-bucket local CSR (rowptr + srcl) ----------------
__global__ void __launch_bounds__(1024) k_bucket(const unsigned* __restrict__ pairs,
                                                 const int* __restrict__ boff,
                                                 int* __restrict__ rowptr, int* __restrict__ srcl) {
    __shared__ int sh[1024];
    __shared__ int se[1024];
    int b = blockIdx.x, tid = threadIdx.x;
    int bb = boff[b], be = boff[b + 1];
    sh[tid] = 0;
    __syncthreads();
    for (int k = bb + tid; k < be; k += 1024) atomicAdd(&sh[pairs[k] >> 17], 1);
    __syncthreads();
    int deg = sh[tid];
    se[tid] = deg;
    __syncthreads();
    for (int off = 1; off < 1024; off <<= 1) {
        int t = (tid >= off) ? se[tid - off] : 0;
        __syncthreads();
        se[tid] += t;
        __syncthreads();
    }
    int excl = se[tid] - deg;
    int node = (b << 10) + tid;
    if (node < NN) rowptr[node] = bb + excl;
    sh[tid] = bb + excl;     // cursor
    __syncthreads();
    for (int k = bb + tid; k < be; k += 1024) {
        unsigned p = pairs[k];
        int pos = atomicAdd(&sh[p >> 17], 1);
        srcl[pos] = (int)(p & 0x1FFFFu);
    }
    if (b == 0 && tid == 0) rowptr[NN] = ET;
}

// ---------------- BN apply + linear(2->64) + attention scalars ----------------
__global__ void k_xform1(const float* __restrict__ h, const float* __restrict__ stats,
                         const float* __restrict__ gamma, const float* __restrict__ beta,
                         const float* __restrict__ W1, const float* __restrict__ a_s,
                         const float* __restrict__ a_d,
                         float* __restrict__ xp, float* __restrict__ es, float* __restrict__ ed) {
    int n = blockIdx.x * blockDim.x + threadIdx.x;
    if (n >= NN) return;
    const float inv = 1.f / (float)NN;
    float mu0 = stats[0] * inv, mu1 = stats[1] * inv;
    float v0 = stats[2] * inv - mu0 * mu0;
    float v1 = stats[3] * inv - mu1 * mu1;
    float g0 = rsqrtf(v0 + 1e-5f) * gamma[0];
    float g1 = rsqrtf(v1 + 1e-5f) * gamma[1];
    float2 hv = reinterpret_cast<const float2*>(h)[n];
    float x0 = (hv.x - mu0) * g0 + beta[0];
    float x1 = (hv.y - mu1) * g1 + beta[1];
    float vv[64];
    float es0 = 0.f, es1 = 0.f, ed0 = 0.f, ed1 = 0.f;
#pragma unroll
    for (int f = 0; f < 64; ++f) {
        float v = x0 * W1[2 * f] + x1 * W1[2 * f + 1];
        vv[f] = v;
        float ts = v * a_s[f], td = v * a_d[f];
        if (f < 32) { es0 += ts; ed0 += td; } else { es1 += ts; ed1 += td; }
    }
    f4* xo = reinterpret_cast<f4*>(xp + (size_t)n * 64);
#pragma unroll
    for (int q = 0; q < 16; ++q)
        xo[q] = make_float4(vv[4 * q], vv[4 * q + 1], vv[4 * q + 2], vv[4 * q + 3]);
    es[2 * n] = es0; es[2 * n + 1] = es1;
    ed[2 * n] = ed0; ed[2 * n + 1] = ed1;
}

// ---------------- GAT aggregation: one wave per dst node, online softmax ----------------
__global__ void __launch_bounds__(256) k_gat(
    const float* __restrict__ xp, const float* __restrict__ es, const float* __restrict__ ed,
    const int* __restrict__ rowptr, const int* __restrict__ srcl,
    const float* __restrict__ bias, float* __restrict__ out) {
    int wid = (blockIdx.x * blockDim.x + threadIdx.x) >> 6;   // wave id == node
    int lane = threadIdx.x & 63;
    if (wid >= NN) return;
    int n = wid;
    int head = lane >> 5;
    int beg = rowptr[n], end = rowptr[n + 1];
    float edn = ed[2 * n + head];
    float m = -1e30f, sum = 0.f, acc = 0.f;
    int k = beg;
    for (; k + 4 <= end; k += 4) {
        int s0 = srcl[k], s1 = srcl[k + 1], s2 = srcl[k + 2], s3 = srcl[k + 3];
        float e0 = es[2 * s0 + head] + edn;
        float e1 = es[2 * s1 + head] + edn;
        float e2 = es[2 * s2 + head] + edn;
        float e3 = es[2 * s3 + head] + edn;
        float x0 = xp[(size_t)s0 * 64 + lane];
        float x1 = xp[(size_t)s1 * 64 + lane];
        float x2 = xp[(size_t)s2 * 64 + lane];
        float x3 = xp[(size_t)s3 * 64 + lane];
        e0 = (e0 > 0.f) ? e0 : NEG * e0;
        e1 = (e1 > 0.f) ? e1 : NEG * e1;
        e2 = (e2 > 0.f) ? e2 : NEG * e2;
        e3 = (e3 > 0.f) ? e3 : NEG * e3;
        float mn = fmaxf(m, fmaxf(fmaxf(e0, e1), fmaxf(e2, e3)));
        float sc = __expf(m - mn);
        float w0 = __expf(e0 - mn);
        float w1 = __expf(e1 - mn);
        float w2 = __expf(e2 - mn);
        float w3 = __expf(e3 - mn);
        sum = sum * sc + (w0 + w1) + (w2 + w3);
        acc = acc * sc + (w0 * x0 + w1 * x1) + (w2 * x2 + w3 * x3);
        m = mn;
    }
    for (; k < end; ++k) {
        int s = srcl[k];
        float e = es[2 * s + head] + edn;
        e = (e > 0.f) ? e : NEG * e;
        float xv = xp[(size_t)s * 64 + lane];
        float mn = fmaxf(m, e);
        float sc = __expf(m - mn);
        float w  = __expf(e - mn);
        sum = sum * sc + w;
        acc = acc * sc + w * xv;
        m = mn;
    }
    float r = acc / (sum + 1e-16f) + bias[lane];
    out[(size_t)n * 64 + lane] = fmaxf(r, 0.f);               // post-GAT ReLU (both layers)
}

// ---------------- linear(64->64) + attention scalars (for GAT layer 2) ----------------
__global__ void k_xform2(const float* __restrict__ hin, const float* __restrict__ W,
                         const float* __restrict__ a_s, const float* __restrict__ a_d,
                         float* __restrict__ xp, float* __restrict__ es, float* __restrict__ ed) {
    int n = blockIdx.x * blockDim.x + threadIdx.x;
    if (n >= NN) return;
    float x[64];
    const f4* xi = reinterpret_cast<const f4*>(hin + (size_t)n * 64);
#pragma unroll
    for (int q = 0; q < 16; ++q) {
        f4 t = xi[q];
        x[4 * q] = t.x; x[4 * q + 1] = t.y; x[4 * q + 2] = t.z; x[4 * q + 3] = t.w;
    }
    float es0 = 0.f, es1 = 0.f, ed0 = 0.f, ed1 = 0.f;
    f4* xo = reinterpret_cast<f4*>(xp + (size_t)n * 64);
#pragma unroll 1
    for (int fq = 0; fq < 16; ++fq) {
        float vq[4];
#pragma unroll
        for (int j = 0; j < 4; ++j) {
            int f = 4 * fq + j;
            float acc = 0.f;
#pragma unroll
            for (int i = 0; i < 64; ++i) acc += W[f * 64 + i] * x[i];
            vq[j] = acc;
            float ts = acc * a_s[f], td = acc * a_d[f];
            if (fq < 8) { es0 += ts; ed0 += td; } else { es1 += ts; ed1 += td; }
        }
        xo[fq] = make_float4(vq[0], vq[1], vq[2], vq[3]);
    }
    es[2 * n] = es0; es[2 * n + 1] = es1;
    ed[2 * n] = ed0; ed[2 * n + 1] = ed1;
}

// ---------------- fused 5-layer MLP: 4 waves/block, wave w owns outputs [16w,16w+16),
// ---------------- packed weights -> contiguous wave-uniform s_load streams ----------------
__device__ __forceinline__ void mlayer(const float* __restrict__ Wq, const float* __restrict__ B,
                                       int o0, const float* __restrict__ xrow, float* acc) {
#pragma unroll
    for (int j = 0; j < 16; ++j) acc[j] = B[o0 + j];
#pragma unroll
    for (int c = 0; c < 4; ++c) {
        float xc[16];
#pragma unroll
        for (int q = 0; q < 4; ++q) {
            f4 t = *reinterpret_cast<const f4*>(&xrow[c * 16 + 4 * q]);
            xc[4 * q] = t.x; xc[4 * q + 1] = t.y; xc[4 * q + 2] = t.z; xc[4 * q + 3] = t.w;
        }
#pragma unroll
        for (int i = 0; i < 16; ++i) {
            const float* row = &Wq[(c * 16 + i) * 16];   // 64 B contiguous, wave-uniform
#pragma unroll
            for (int j = 0; j < 16; ++j) acc[j] += row[j] * xc[i];
        }
    }
}

__global__ void __launch_bounds__(256) k_mlp(
    const float* __restrict__ hin,
    const float* __restrict__ Wt, const float* __restrict__ Wt5,
    const float* __restrict__ b1, const float* __restrict__ b2,
    const float* __restrict__ b3, const float* __restrict__ b4,
    const float* __restrict__ b5,
    float* __restrict__ out) {
    __shared__ float xs[64 * MSTR];
    int lane = threadIdx.x & 63;
    int w = __builtin_amdgcn_readfirstlane(threadIdx.x >> 6);
    int nodeBase = blockIdx.x * 64;
    int node = nodeBase + lane;
    int o0 = w * 16;
    const float* xrow = &xs[lane * MSTR];

    // cooperative, coalesced load of 64 nodes x 64 floats into LDS
#pragma unroll
    for (int i = 0; i < 4; ++i) {
        int v = threadIdx.x + 256 * i;
        int nl = v >> 4;
        int f = (v & 15) << 2;
        f4 t4 = make_float4(0.f, 0.f, 0.f, 0.f);
        if (nodeBase + nl < NN)
            t4 = reinterpret_cast<const f4*>(hin)[(size_t)(nodeBase + nl) * 16 + (v & 15)];
        *reinterpret_cast<f4*>(&xs[nl * MSTR + f]) = t4;
    }
    __syncthreads();

    float acc[16];
#define MLP_LAYER(L, Bp)                                                         \
    mlayer(Wt + ((L) * 4 + w) * 1024, Bp, o0, xrow, acc);                        \
    __syncthreads();                                                             \
    _Pragma("unroll")                                                            \
    for (int j = 0; j < 16; j += 4)                                              \
        *reinterpret_cast<f4*>(&xs[lane * MSTR + o0 + j]) =                      \
            make_float4(fmaxf(acc[j], 0.f), fmaxf(acc[j + 1], 0.f),              \
                        fmaxf(acc[j + 2], 0.f), fmaxf(acc[j + 3], 0.f));         \
    __syncthreads();

    MLP_LAYER(0, b1)
    MLP_LAYER(1, b2)
    MLP_LAYER(2, b3)
    MLP_LAYER(3, b4)
#undef MLP_LAYER

    // final 64 -> 11: wave w computes outputs [3w, 3w+ocnt) via packed Wt5 columns
    int ocnt = (w == 3) ? 2 : 3;
    int ob = w * 3;
    float a5[3];
#pragma unroll
    for (int j = 0; j < 3; ++j) a5[j] = (j < ocnt) ? b5[ob + j] : 0.f;
#pragma unroll
    for (int c = 0; c < 4; ++c) {
        float xc[16];
#pragma unroll
        for (int q = 0; q < 4; ++q) {
            f4 t = *reinterpret_cast<const f4*>(&xrow[c * 16 + 4 * q]);
            xc[4 * q] = t.x; xc[4 * q + 1] = t.y; xc[4 * q + 2] = t.z; xc[4 * q + 3] = t.w;
        }
#pragma unroll
        for (int i = 0; i < 16; ++i) {
            const float* row = &Wt5[(c * 16 + i) * 16 + 4 * w];  // 16B aligned, uniform
#pragma unroll
            for (int j = 0; j < 3; ++j) a5[j] += row[j] * xc[i];
        }
    }
    if (node < NN) {
        for (int j = 0; j < ocnt; ++j) out[(size_t)node * 11 + ob + j] = a5[j];
    }
}

// ---------------- launch ----------------
extern "C" void kernel_launch(void* const* d_in, const int* in_sizes, int n_in,
                              void* d_out, int out_size, void* d_ws, size_t ws_size,
                              hipStream_t stream) {
    const float* h   = (const float*)d_in[0];
    const int*   ei  = (const int*)d_in[1];
    const float* gam = (const float*)d_in[2];
    const float* bet = (const float*)d_in[3];
    const float* W1  = (const float*)d_in[4];
    const float* as1 = (const float*)d_in[5];
    const float* ad1 = (const float*)d_in[6];
    const float* b1  = (const float*)d_in[7];
    const float* W2  = (const float*)d_in[8];
    const float* as2 = (const float*)d_in[9];
    const float* ad2 = (const float*)d_in[10];
    const float* b2  = (const float*)d_in[11];
    const float* fw1 = (const float*)d_in[12];
    const float* fb1 = (const float*)d_in[13];
    const float* fw2 = (const float*)d_in[14];
    const float* fb2 = (const float*)d_in[15];
    const float* fw3 = (const float*)d_in[16];
    const float* fb3 = (const float*)d_in[17];
    const float* fw4 = (const float*)d_in[18];
    const float* fb4 = (const float*)d_in[19];
    const float* fw5 = (const float*)d_in[20];
    const float* fb5 = (const float*)d_in[21];
    float* out = (float*)d_out;

    char* ws = (char*)d_ws;
    size_t off = 0;
    auto alloc = [&](size_t bytes) -> char* {
        char* p = ws + off;
        off += (bytes + 255) & ~(size_t)255;
        return p;
    };
    float* stats  = (float*)alloc(4 * sizeof(float));
    int*   H      = (int*)alloc((size_t)NBUCK * NBLK * sizeof(int));
    int*   boff   = (int*)alloc((size_t)(NBUCK + 1) * sizeof(int));
    int*   rowptr = (int*)alloc((size_t)(NN + 1) * sizeof(int));
    int*   srcl   = (int*)alloc((size_t)ET * sizeof(int));
    float* es     = (float*)alloc((size_t)NN * 2 * sizeof(float));
    float* ed     = (float*)alloc((size_t)NN * 2 * sizeof(float));
    float* Wt     = (float*)alloc((size_t)4 * 4 * 64 * 16 * sizeof(float));
    float* Wt5    = (float*)alloc((size_t)64 * 16 * sizeof(float));
    float* bufA   = (float*)alloc((size_t)NN * 64 * sizeof(float));
    float* bufB   = (float*)alloc((size_t)NN * 64 * sizeof(float));
    unsigned* pairs = (unsigned*)bufA;   // alias: pairs dead before k_xform1 writes bufA
    (void)ws_size; (void)in_sizes; (void)n_in; (void)out_size;

    k_init<<<1, 64, 0, stream>>>(stats);
    k_bnstats<<<256, 256, 0, stream>>>(h, stats);
    k_wprep<<<64, 256, 0, stream>>>(fw1, fw2, fw3, fw4, fw5, Wt, Wt5);

    // CSR build: hist -> scan -> partition -> per-bucket CSR
    k_hist<<<NBLK, 256, 0, stream>>>(ei, H);
    k_bscan1<<<1, 1024, 0, stream>>>(H, boff);
    k_bscan2<<<NBUCK, 64, 0, stream>>>(H, boff);
    k_part<<<NBLK, 256, 0, stream>>>(ei, H, pairs);
    k_bucket<<<NBUCK, 1024, 0, stream>>>(pairs, boff, rowptr, srcl);

    // GAT layer 1 (input = BN(h))
    k_xform1<<<(NN + 255) / 256, 256, 0, stream>>>(h, stats, gam, bet, W1, as1, ad1,
                                                   bufA, es, ed);
    k_gat<<<(NN * 64) / 256, 256, 0, stream>>>(bufA, es, ed, rowptr, srcl, b1, bufB);

    // GAT layer 2 (input = bufB)
    k_xform2<<<(NN + 255) / 256, 256, 0, stream>>>(bufB, W2, as2, ad2, bufA, es, ed);
    k_gat<<<(NN * 64) / 256, 256, 0, stream>>>(bufA, es, ed, rowptr, srcl, b2, bufB);

    // MLP head
    k_mlp<<<(NN + 63) / 64, 256, 0, stream>>>(bufB, Wt, Wt5, fb1, fb2, fb3, fb4, fb5, out);
}

// Round 5
// 319.331 us; speedup vs baseline: 2.6558x; 1.2333x over previous
//
#include <hip/hip_runtime.h>
#include <math.h>

#define NN 100000
#define EE 1600000
#define ET (EE + NN)          // edges + self loops = 1,700,000
#define NEG 0.2f
#define MSTR 68               // k_mlp LDS row stride (floats)

// CSR-build geometry
#define NBUCK 98              // ceil(NN/1024) buckets of 1024 dst nodes
#define NBLK 416              // ceil(ET/4096) partition blocks
#define BITEMS 4096           // items per partition block (256 thr x 16)

typedef float4 f4;

// ---------------- init: stats=0 ----------------
__global__ void k_init(float* stats) {
    int i = threadIdx.x;
    if (i < 4) stats[i] = 0.f;
}

// ---------------- BN statistics: sum / sumsq of 2 columns ----------------
__global__ void k_bnstats(const float* __restrict__ h, float* stats) {
    int gid = blockIdx.x * blockDim.x + threadIdx.x;
    int stride = gridDim.x * blockDim.x;
    float s0 = 0.f, s1 = 0.f, q0 = 0.f, q1 = 0.f;
    for (int i = gid; i < NN; i += stride) {
        float2 v = reinterpret_cast<const float2*>(h)[i];
        s0 += v.x; q0 += v.x * v.x;
        s1 += v.y; q1 += v.y * v.y;
    }
#pragma unroll
    for (int off = 32; off >= 1; off >>= 1) {
        s0 += __shfl_xor(s0, off);
        s1 += __shfl_xor(s1, off);
        q0 += __shfl_xor(q0, off);
        q1 += __shfl_xor(q1, off);
    }
    if ((threadIdx.x & 63) == 0) {
        atomicAdd(&stats[0], s0); atomicAdd(&stats[1], s1);
        atomicAdd(&stats[2], q0); atomicAdd(&stats[3], q1);
    }
}

// ---------------- rank-2 attention coefficients: coef[(sd<<2)|(h<<1)|i] = sum_c W1[(h*32+c)*2+i]*a[h*32+c]
__global__ void k_coef(const float* __restrict__ W1, const float* __restrict__ as1,
                       const float* __restrict__ ad1, float* __restrict__ coef) {
    int t = threadIdx.x;
    if (t >= 8) return;
    int sd = t >> 2, hh = (t >> 1) & 1, i = t & 1;
    const float* a = sd ? ad1 : as1;
    float s = 0.f;
    for (int c = 0; c < 32; ++c) s += W1[(hh * 32 + c) * 2 + i] * a[hh * 32 + c];
    coef[t] = s;
}

// ---------------- pack MLP weights for wave-uniform contiguous s_load streams ----------------
__global__ void k_wprep(const float* __restrict__ w1, const float* __restrict__ w2,
                        const float* __restrict__ w3, const float* __restrict__ w4,
                        const float* __restrict__ w5,
                        float* __restrict__ Wt, float* __restrict__ Wt5) {
    int idx = blockIdx.x * blockDim.x + threadIdx.x;
    if (idx < 4 * 4096) {
        int L = idx >> 12;
        int r = idx & 4095;
        int q = r >> 10;
        int t = r & 1023;
        int i = t >> 4, j = t & 15;
        const float* W = (L == 0) ? w1 : (L == 1) ? w2 : (L == 2) ? w3 : w4;
        Wt[idx] = W[(q * 16 + j) * 64 + i];
    }
    if (idx < 1024) {
        int i = idx >> 4, c = idx & 15;
        int w = c >> 2, j = c & 3;
        int o = 3 * w + j;
        int ocnt = (w == 3) ? 2 : 3;
        Wt5[idx] = (j < ocnt) ? w5[o * 64 + i] : 0.f;
    }
}

// ---------------- CSR pass A: per-block bucket histogram ----------------
__global__ void __launch_bounds__(256) k_hist(const int* __restrict__ ei, int* __restrict__ H) {
    __shared__ int hist[NBUCK];
    int tid = threadIdx.x, blk = blockIdx.x;
    if (tid < NBUCK) hist[tid] = 0;
    __syncthreads();
    int base = blk * BITEMS;
#pragma unroll
    for (int it = 0; it < 16; ++it) {
        int i = base + it * 256 + tid;
        if (i < ET) {
            int d = (i < EE) ? ei[EE + i] : (i - EE);
            atomicAdd(&hist[d >> 10], 1);
        }
    }
    __syncthreads();
    if (tid < NBUCK) H[tid * NBLK + blk] = hist[tid];
}

// ---------------- CSR pass B1: bucket totals + base offsets (1 block) ----------------
__global__ void __launch_bounds__(1024) k_bscan1(const int* __restrict__ H, int* __restrict__ boff) {
    __shared__ int part[1024];
    __shared__ int btot[NBUCK];
    int tid = threadIdx.x;
    int b = tid >> 3, k = tid & 7;
    int s = 0;
    if (b < NBUCK)
        for (int blk = k; blk < NBLK; blk += 8) s += H[b * NBLK + blk];
    part[tid] = s;
    __syncthreads();
    if (tid < NBUCK) {
        int t = 0;
#pragma unroll
        for (int j = 0; j < 8; ++j) t += part[tid * 8 + j];
        btot[tid] = t;
    }
    __syncthreads();
    if (tid == 0) {
        int run = 0;
        for (int bb = 0; bb < NBUCK; ++bb) { boff[bb] = run; run += btot[bb]; }
        boff[NBUCK] = ET;
    }
}

// ---------------- CSR pass B2: per-(bucket,block) absolute offsets ----------------
__global__ void __launch_bounds__(64) k_bscan2(int* __restrict__ H, const int* __restrict__ boff) {
    int b = blockIdx.x, lane = threadIdx.x;
    int s = 0;
    int base_i = lane * 7;
#pragma unroll
    for (int j = 0; j < 7; ++j) {
        int idx = base_i + j;
        if (idx < NBLK) s += H[b * NBLK + idx];
    }
    int incl = s;
#pragma unroll
    for (int d = 1; d < 64; d <<= 1) {
        int n = __shfl_up(incl, d, 64);
        if (lane >= d) incl += n;
    }
    int run = boff[b] + incl - s;
#pragma unroll
    for (int j = 0; j < 7; ++j) {
        int idx = base_i + j;
        if (idx < NBLK) {
            int t = H[b * NBLK + idx];
            H[b * NBLK + idx] = run;
            run += t;
        }
    }
}

// ---------------- CSR pass C: partition edges into bucket regions ----------------
__global__ void __launch_bounds__(256) k_part(const int* __restrict__ ei, const int* __restrict__ H,
                                              unsigned* __restrict__ pairs) {
    __shared__ int cur[NBUCK];
    int tid = threadIdx.x, blk = blockIdx.x;
    if (tid < NBUCK) cur[tid] = H[tid * NBLK + blk];
    __syncthreads();
    int base = blk * BITEMS;
#pragma unroll
    for (int it = 0; it < 16; ++it) {
        int i = base + it * 256 + tid;
        if (i < ET) {
            int s, d;
            if (i < EE) { s = ei[i]; d = ei[EE + i]; }
            else { s = d = i - EE; }
            int b = d >> 10;
            int pos = atomicAdd(&cur[b], 1);
            pairs[pos] = (unsigned)s | ((unsigned)(d & 1023) << 17);
        }
    }
}

// ---------------- CSR pass D: per-bucket local CSR (rowptr + srcl) ----------------
__global__ void __launch_bounds__(1024) k_bucket(const unsigned* __restrict__ pairs,
                                                 const int* __restrict__ boff,
                                                 int* __restrict__ rowptr, int* __restrict__ srcl) {
    __shared__ int sh[1024];
    __shared__ int se[1024];
    int b = blockIdx.x, tid = threadIdx.x;
    int bb = boff[b], be = boff[b + 1];
    sh[tid] = 0;
    __syncthreads();
    for (int k = bb + tid; k < be; k += 1024) atomicAdd(&sh[pairs[k] >> 17], 1);
    __syncthreads();
    int deg = sh[tid];
    se[tid] = deg;
    __syncthreads();
    for (int off = 1; off < 1024; off <<= 1) {
        int t = (tid >= off) ? se[tid - off] : 0;
        __syncthreads();
        se[tid] += t;
        __syncthreads();
    }
    int excl = se[tid] - deg;
    int node = (b << 10) + tid;
    if (node < NN) rowptr[node] = bb + excl;
    sh[tid] = bb + excl;     // cursor
    __syncthreads();
    for (int k = bb + tid; k < be; k += 1024) {
        unsigned p = pairs[k];
        int pos = atomicAdd(&sh[p >> 17], 1);
        srcl[pos] = (int)(p & 0x1FFFFu);
    }
    if (b == 0 && tid == 0) rowptr[NN] = ET;
}

// ---------------- layer-1 prep: BN apply + rank-2 attention scalars, packed node record ----------------
// nd1[n] = {es_h0, es_h1, x0, x1}; ed1[n] = {ed_h0, ed_h1}
__global__ void k_prep1(const float* __restrict__ h, const float* __restrict__ stats,
                        const float* __restrict__ gamma, const float* __restrict__ beta,
                        const float* __restrict__ coef,
                        f4* __restrict__ nd1, float2* __restrict__ ed1) {
    int n = blockIdx.x * blockDim.x + threadIdx.x;
    if (n >= NN) return;
    const float inv = 1.f / (float)NN;
    float mu0 = stats[0] * inv, mu1 = stats[1] * inv;
    float v0 = stats[2] * inv - mu0 * mu0;
    float v1 = stats[3] * inv - mu1 * mu1;
    float g0 = rsqrtf(v0 + 1e-5f) * gamma[0];
    float g1 = rsqrtf(v1 + 1e-5f) * gamma[1];
    float2 hv = reinterpret_cast<const float2*>(h)[n];
    float x0 = (hv.x - mu0) * g0 + beta[0];
    float x1 = (hv.y - mu1) * g1 + beta[1];
    float es0 = x0 * coef[0] + x1 * coef[1];
    float es1 = x0 * coef[2] + x1 * coef[3];
    float ed0 = x0 * coef[4] + x1 * coef[5];
    float ed1v = x0 * coef[6] + x1 * coef[7];
    nd1[n] = make_float4(es0, es1, x0, x1);
    ed1[n] = make_float2(ed0, ed1v);
}

// ---------------- layer-1 GAT: thread per dst node, 16B gather from L2-resident nd1 ----------------
// plain exp (args bounded |e|<~3): softmax shift-invariant, no running max needed
__global__ void __launch_bounds__(256) k_gat1(
    const f4* __restrict__ nd1, const float2* __restrict__ ed1,
    const int* __restrict__ rowptr, const int* __restrict__ srcl,
    f4* __restrict__ agg1a, float2* __restrict__ agg1s) {
    int n = blockIdx.x * blockDim.x + threadIdx.x;
    if (n >= NN) return;
    int beg = rowptr[n], end = rowptr[n + 1];
    float2 ed = ed1[n];
    float A0 = 0.f, B0 = 0.f, S0 = 0.f, A1 = 0.f, B1 = 0.f, S1 = 0.f;
    for (int k = beg; k < end; ++k) {
        int s = srcl[k];
        f4 p = nd1[s];
        float e0 = p.x + ed.x;
        float e1 = p.y + ed.y;
        e0 = (e0 > 0.f) ? e0 : NEG * e0;
        e1 = (e1 > 0.f) ? e1 : NEG * e1;
        float w0 = __expf(e0);
        float w1 = __expf(e1);
        A0 += w0 * p.z; B0 += w0 * p.w; S0 += w0;
        A1 += w1 * p.z; B1 += w1 * p.w; S1 += w1;
    }
    agg1a[n] = make_float4(A0, B0, A1, B1);
    agg1s[n] = make_float2(S0, S1);
}

// ---------------- layer-1 finalize + linear(64->64) + attention scalars for layer 2 ----------------
__global__ void k_xform2f(const f4* __restrict__ agg1a, const float2* __restrict__ agg1s,
                          const float* __restrict__ W1, const float* __restrict__ b1,
                          const float* __restrict__ W, const float* __restrict__ a_s,
                          const float* __restrict__ a_d,
                          float* __restrict__ xp, float* __restrict__ es, float* __restrict__ ed) {
    int n = blockIdx.x * blockDim.x + threadIdx.x;
    if (n >= NN) return;
    f4 ag = agg1a[n];
    float2 sg = agg1s[n];
    float r0 = 1.f / (sg.x + 1e-16f);
    float r1 = 1.f / (sg.y + 1e-16f);
    float x[64];
#pragma unroll
    for (int f = 0; f < 64; ++f) {
        float A = (f < 32) ? ag.x : ag.z;
        float B = (f < 32) ? ag.y : ag.w;
        float r = (f < 32) ? r0 : r1;
        x[f] = fmaxf((A * W1[2 * f] + B * W1[2 * f + 1]) * r + b1[f], 0.f);
    }
    float es0 = 0.f, es1 = 0.f, ed0 = 0.f, ed1 = 0.f;
    f4* xo = reinterpret_cast<f4*>(xp + (size_t)n * 64);
#pragma unroll 1
    for (int fq = 0; fq < 16; ++fq) {
        float vq[4];
#pragma unroll
        for (int j = 0; j < 4; ++j) {
            int f = 4 * fq + j;
            float acc = 0.f;
#pragma unroll
            for (int i = 0; i < 64; ++i) acc += W[f * 64 + i] * x[i];
            vq[j] = acc;
            float ts = acc * a_s[f], td = acc * a_d[f];
            if (fq < 8) { es0 += ts; ed0 += td; } else { es1 += ts; ed1 += td; }
        }
        xo[fq] = make_float4(vq[0], vq[1], vq[2], vq[3]);
    }
    es[2 * n] = es0; es[2 * n + 1] = es1;
    ed[2 * n] = ed0; ed[2 * n + 1] = ed1;
}

// ---------------- layer-2 GAT: one wave per dst node, plain-exp softmax ----------------
__global__ void __launch_bounds__(256) k_gat(
    const float* __restrict__ xp, const float* __restrict__ es, const float* __restrict__ ed,
    const int* __restrict__ rowptr, const int* __restrict__ srcl,
    const float* __restrict__ bias, float* __restrict__ out) {
    int wid = (blockIdx.x * blockDim.x + threadIdx.x) >> 6;   // wave id == node
    int lane = threadIdx.x & 63;
    if (wid >= NN) return;
    int n = wid;
    int head = lane >> 5;
    int beg = rowptr[n], end = rowptr[n + 1];
    float edn = ed[2 * n + head];
    float sum = 0.f, acc = 0.f;
    int k = beg;
    for (; k + 4 <= end; k += 4) {
        int s0 = srcl[k], s1 = srcl[k + 1], s2 = srcl[k + 2], s3 = srcl[k + 3];
        float e0 = es[2 * s0 + head] + edn;
        float e1 = es[2 * s1 + head] + edn;
        float e2 = es[2 * s2 + head] + edn;
        float e3 = es[2 * s3 + head] + edn;
        float x0 = xp[(size_t)s0 * 64 + lane];
        float x1 = xp[(size_t)s1 * 64 + lane];
        float x2 = xp[(size_t)s2 * 64 + lane];
        float x3 = xp[(size_t)s3 * 64 + lane];
        e0 = (e0 > 0.f) ? e0 : NEG * e0;
        e1 = (e1 > 0.f) ? e1 : NEG * e1;
        e2 = (e2 > 0.f) ? e2 : NEG * e2;
        e3 = (e3 > 0.f) ? e3 : NEG * e3;
        float w0 = __expf(e0);
        float w1 = __expf(e1);
        float w2 = __expf(e2);
        float w3 = __expf(e3);
        sum += (w0 + w1) + (w2 + w3);
        acc += (w0 * x0 + w1 * x1) + (w2 * x2 + w3 * x3);
    }
    for (; k < end; ++k) {
        int s = srcl[k];
        float e = es[2 * s + head] + edn;
        e = (e > 0.f) ? e : NEG * e;
        float w = __expf(e);
        sum += w;
        acc += w * xp[(size_t)s * 64 + lane];
    }
    float r = acc / (sum + 1e-16f) + bias[lane];
    out[(size_t)n * 64 + lane] = fmaxf(r, 0.f);               // post-GAT ReLU
}

// ---------------- fused 5-layer MLP: 4 waves/block, wave w owns outputs [16w,16w+16) ----------------
__device__ __forceinline__ void mlayer(const float* __restrict__ Wq, const float* __restrict__ B,
                                       int o0, const float* __restrict__ xrow, float* acc) {
#pragma unroll
    for (int j = 0; j < 16; ++j) acc[j] = B[o0 + j];
#pragma unroll
    for (int c = 0; c < 4; ++c) {
        float xc[16];
#pragma unroll
        for (int q = 0; q < 4; ++q) {
            f4 t = *reinterpret_cast<const f4*>(&xrow[c * 16 + 4 * q]);
            xc[4 * q] = t.x; xc[4 * q + 1] = t.y; xc[4 * q + 2] = t.z; xc[4 * q + 3] = t.w;
        }
#pragma unroll
        for (int i = 0; i < 16; ++i) {
            const float* row = &Wq[(c * 16 + i) * 16];   // 64 B contiguous, wave-uniform
#pragma unroll
            for (int j = 0; j < 16; ++j) acc[j] += row[j] * xc[i];
        }
    }
}

__global__ void __launch_bounds__(256) k_mlp(
    const float* __restrict__ hin,
    const float* __restrict__ Wt, const float* __restrict__ Wt5,
    const float* __restrict__ b1, const float* __restrict__ b2,
    const float* __restrict__ b3, const float* __restrict__ b4,
    const float* __restrict__ b5,
    float* __restrict__ out) {
    __shared__ float xs[64 * MSTR];
    int lane = threadIdx.x & 63;
    int w = __builtin_amdgcn_readfirstlane(threadIdx.x >> 6);
    int nodeBase = blockIdx.x * 64;
    int node = nodeBase + lane;
    int o0 = w * 16;
    const float* xrow = &xs[lane * MSTR];

#pragma unroll
    for (int i = 0; i < 4; ++i) {
        int v = threadIdx.x + 256 * i;
        int nl = v >> 4;
        int f = (v & 15) << 2;
        f4 t4 = make_float4(0.f, 0.f, 0.f, 0.f);
        if (nodeBase + nl < NN)
            t4 = reinterpret_cast<const f4*>(hin)[(size_t)(nodeBase + nl) * 16 + (v & 15)];
        *reinterpret_cast<f4*>(&xs[nl * MSTR + f]) = t4;
    }
    __syncthreads();

    float acc[16];
#define MLP_LAYER(L, Bp)                                                         \
    mlayer(Wt + ((L) * 4 + w) * 1024, Bp, o0, xrow, acc);                        \
    __syncthreads();                                                             \
    _Pragma("unroll")                                                            \
    for (int j = 0; j < 16; j += 4)                                              \
        *reinterpret_cast<f4*>(&xs[lane * MSTR + o0 + j]) =                      \
            make_float4(fmaxf(acc[j], 0.f), fmaxf(acc[j + 1], 0.f),              \
                        fmaxf(acc[j + 2], 0.f), fmaxf(acc[j + 3], 0.f));         \
    __syncthreads();

    MLP_LAYER(0, b1)
    MLP_LAYER(1, b2)
    MLP_LAYER(2, b3)
    MLP_LAYER(3, b4)
#undef MLP_LAYER

    int ocnt = (w == 3) ? 2 : 3;
    int ob = w * 3;
    float a5[3];
#pragma unroll
    for (int j = 0; j < 3; ++j) a5[j] = (j < ocnt) ? b5[ob + j] : 0.f;
#pragma unroll
    for (int c = 0; c < 4; ++c) {
        float xc[16];
#pragma unroll
        for (int q = 0; q < 4; ++q) {
            f4 t = *reinterpret_cast<const f4*>(&xrow[c * 16 + 4 * q]);
            xc[4 * q] = t.x; xc[4 * q + 1] = t.y; xc[4 * q + 2] = t.z; xc[4 * q + 3] = t.w;
        }
#pragma unroll
        for (int i = 0; i < 16; ++i) {
            const float* row = &Wt5[(c * 16 + i) * 16 + 4 * w];
#pragma unroll
            for (int j = 0; j < 3; ++j) a5[j] += row[j] * xc[i];
        }
    }
    if (node < NN) {
        for (int j = 0; j < ocnt; ++j) out[(size_t)node * 11 + ob + j] = a5[j];
    }
}

// ---------------- launch ----------------
extern "C" void kernel_launch(void* const* d_in, const int* in_sizes, int n_in,
                              void* d_out, int out_size, void* d_ws, size_t ws_size,
                              hipStream_t stream) {
    const float* h   = (const float*)d_in[0];
    const int*   ei  = (const int*)d_in[1];
    const float* gam = (const float*)d_in[2];
    const float* bet = (const float*)d_in[3];
    const float* W1  = (const float*)d_in[4];
    const float* as1 = (const float*)d_in[5];
    const float* ad1 = (const float*)d_in[6];
    const float* b1  = (const float*)d_in[7];
    const float* W2  = (const float*)d_in[8];
    const float* as2 = (const float*)d_in[9];
    const float* ad2 = (const float*)d_in[10];
    const float* b2  = (const float*)d_in[11];
    const float* fw1 = (const float*)d_in[12];
    const float* fb1 = (const float*)d_in[13];
    const float* fw2 = (const float*)d_in[14];
    const float* fb2 = (const float*)d_in[15];
    const float* fw3 = (const float*)d_in[16];
    const float* fb3 = (const float*)d_in[17];
    const float* fw4 = (const float*)d_in[18];
    const float* fb4 = (const float*)d_in[19];
    const float* fw5 = (const float*)d_in[20];
    const float* fb5 = (const float*)d_in[21];
    float* out = (float*)d_out;

    char* ws = (char*)d_ws;
    size_t off = 0;
    auto alloc = [&](size_t bytes) -> char* {
        char* p = ws + off;
        off += (bytes + 255) & ~(size_t)255;
        return p;
    };
    float* stats  = (float*)alloc(4 * sizeof(float));
    float* coef   = (float*)alloc(8 * sizeof(float));
    int*   H      = (int*)alloc((size_t)NBUCK * NBLK * sizeof(int));
    int*   boff   = (int*)alloc((size_t)(NBUCK + 1) * sizeof(int));
    int*   rowptr = (int*)alloc((size_t)(NN + 1) * sizeof(int));
    int*   srcl   = (int*)alloc((size_t)ET * sizeof(int));
    float* es     = (float*)alloc((size_t)NN * 2 * sizeof(float));
    float* ed     = (float*)alloc((size_t)NN * 2 * sizeof(float));
    float* Wt     = (float*)alloc((size_t)4 * 4 * 64 * 16 * sizeof(float));
    float* Wt5    = (float*)alloc((size_t)64 * 16 * sizeof(float));
    float* bufA   = (float*)alloc((size_t)NN * 64 * sizeof(float));
    float* bufB   = (float*)alloc((size_t)NN * 64 * sizeof(float));
    // aliases into bufA/bufB (dead before their hosts are written):
    unsigned* pairs = (unsigned*)bufA;                    // dead after k_bucket; bufA written by k_xform2f
    f4*     agg1a = (f4*)bufB;                            // dead after k_xform2f; bufB written by k_gat
    float2* agg1s = (float2*)(bufB + (size_t)NN * 4);
    f4*     nd1   = (f4*)(bufB + (size_t)NN * 6);
    float2* ed1   = (float2*)(bufB + (size_t)NN * 10);
    (void)ws_size; (void)in_sizes; (void)n_in; (void)out_size;

    k_init<<<1, 64, 0, stream>>>(stats);
    k_bnstats<<<256, 256, 0, stream>>>(h, stats);
    k_coef<<<1, 64, 0, stream>>>(W1, as1, ad1, coef);
    k_wprep<<<64, 256, 0, stream>>>(fw1, fw2, fw3, fw4, fw5, Wt, Wt5);

    // CSR build: hist -> scan -> partition -> per-bucket CSR
    k_hist<<<NBLK, 256, 0, stream>>>(ei, H);
    k_bscan1<<<1, 1024, 0, stream>>>(H, boff);
    k_bscan2<<<NBUCK, 64, 0, stream>>>(H, boff);
    k_part<<<NBLK, 256, 0, stream>>>(ei, H, pairs);
    k_bucket<<<NBUCK, 1024, 0, stream>>>(pairs, boff, rowptr, srcl);

    // GAT layer 1 (rank-2 path: 16B/edge gather, scalar accumulators)
    k_prep1<<<(NN + 255) / 256, 256, 0, stream>>>(h, stats, gam, bet, coef, nd1, ed1);
    k_gat1<<<(NN + 255) / 256, 256, 0, stream>>>(nd1, ed1, rowptr, srcl, agg1a, agg1s);

    // layer-1 finalize + layer-2 transform (writes xp2=bufA, es, ed)
    k_xform2f<<<(NN + 255) / 256, 256, 0, stream>>>(agg1a, agg1s, W1, b1, W2, as2, ad2,
                                                    bufA, es, ed);
    // GAT layer 2 (full 64-dim gather)
    k_gat<<<(NN * 64) / 256, 256, 0, stream>>>(bufA, es, ed, rowptr, srcl, b2, bufB);

    // MLP head
    k_mlp<<<(NN + 63) / 64, 256, 0, stream>>>(bufB, Wt, Wt5, fb1, fb2, fb3, fb4, fb5, out);
}